// Round 1
// baseline (1576.556 us; speedup 1.0000x reference)
//
#include <hip/hip_runtime.h>
#include <cstddef>

constexpr int B = 32, L = 512, D = 256, F = 256, T = 2048, NB = 256;
constexpr float LN_EPS = 1e-5f;
constexpr int TILE_T = 32;   // output rows per block
constexpr int TPW = 8;       // rows per wave (4 waves * 8 = 32)
constexpr int BDIM = 256;

// ---------------- cumsum over durations (per batch row) ----------------
__global__ void cumsum_kernel(const int* __restrict__ dt, int* __restrict__ cum) {
    __shared__ int s[L];
    const int b = blockIdx.x, tid = threadIdx.x;
    s[tid] = dt[b * L + tid];
    __syncthreads();
    for (int off = 1; off < L; off <<= 1) {
        int v = (tid >= off) ? s[tid - off] : 0;
        __syncthreads();
        s[tid] += v;
        __syncthreads();
    }
    cum[b * L + tid] = s[tid];
}

// ---------------- length regulator gather: h[b,t,:] = x[b,idx,:] or 0 ----
__global__ void lr_gather_kernel(const float* __restrict__ x, const int* __restrict__ cum,
                                 float* __restrict__ h) {
    const int wave = threadIdx.x >> 6, lane = threadIdx.x & 63;
    const int row = blockIdx.x * 4 + wave;     // b*T + t
    const int b = row / T, t = row % T;
    const int* c = cum + b * L;
    int lo = 0, hi = L;
    while (lo < hi) { const int mid = (lo + hi) >> 1; if (c[mid] <= t) lo = mid + 1; else hi = mid; }
    float4 v = make_float4(0.f, 0.f, 0.f, 0.f);
    if (lo < L) v = *(const float4*)(x + ((size_t)b * L + lo) * D + lane * 4);
    *(float4*)(h + (size_t)row * D + lane * 4) = v;
}

// ---------------- h[b,t,:] += emb[bucketize(tgt[b,t]), :] ----------------
__global__ void add_emb_kernel(const float* __restrict__ tgt, const float* __restrict__ bins,
                               const float* __restrict__ emb, float* __restrict__ h) {
    const int wave = threadIdx.x >> 6, lane = threadIdx.x & 63;
    const int row = blockIdx.x * 4 + wave;     // b*T + t
    const float e = tgt[row];
    int lo = 0, hi = NB - 1;
    while (lo < hi) { const int mid = (lo + hi) >> 1; if (bins[mid] < e) lo = mid + 1; else hi = mid; }
    const size_t off = (size_t)row * D + lane * 4;
    float4 hv = *(float4*)(h + off);
    const float4 ev = *(const float4*)(emb + (size_t)lo * D + lane * 4);
    hv.x += ev.x; hv.y += ev.y; hv.z += ev.z; hv.w += ev.w;
    *(float4*)(h + off) = hv;
}

// ---------------- fused conv1d(k=3,SAME) + bias + ReLU + LayerNorm -------
// DOT=false: write normalized rows to out [Tlen, F]
// DOT=true : additionally dot with lw, +lb, ReLU -> out [Tlen] (scalar per row)
template <bool DOT>
__launch_bounds__(BDIM)
__global__ void conv_ln_kernel(const float* __restrict__ in, int Tlen,
                               const float* __restrict__ w,      // [3, 256, 256] (k, d, f)
                               const float* __restrict__ cb,     // [256]
                               const float* __restrict__ gamma,  // [256]
                               const float* __restrict__ beta,   // [256]
                               const float* __restrict__ lw,     // [256] (DOT only)
                               const float* __restrict__ lb,     // [1]   (DOT only)
                               float* __restrict__ out) {
    __shared__ float in_s[TILE_T + 2][D];   // 34*256*4 = 34.8 KB
    const int b = blockIdx.y;
    const int t0 = blockIdx.x * TILE_T;
    const int tid = threadIdx.x;
    const int g = tid >> 6;        // wave id -> t-group
    const int lane = tid & 63;
    const int f0 = lane * 4;

    // stage rows t0-1 .. t0+TILE_T (zero-padded)
    for (int i = tid; i < (TILE_T + 2) * (D / 4); i += BDIM) {
        const int r = i / (D / 4), c = (i % (D / 4)) * 4;
        const int t = t0 + r - 1;
        float4 v = make_float4(0.f, 0.f, 0.f, 0.f);
        if (t >= 0 && t < Tlen) v = *(const float4*)(in + ((size_t)b * Tlen + t) * D + c);
        *(float4*)(&in_s[r][c]) = v;
    }
    __syncthreads();

    float acc[TPW][4];
    #pragma unroll
    for (int i = 0; i < TPW; i++)
        { acc[i][0] = 0.f; acc[i][1] = 0.f; acc[i][2] = 0.f; acc[i][3] = 0.f; }

    const float* wp = w + f0;
    const int rbase = g * TPW;
    for (int d = 0; d < D; d += 4) {
        float4 r[TPW + 2];
        #pragma unroll
        for (int j = 0; j < TPW + 2; j++)
            r[j] = *(const float4*)(&in_s[rbase + j][d]);   // uniform broadcast
        #pragma unroll
        for (int dd = 0; dd < 4; dd++) {
            #pragma unroll
            for (int k = 0; k < 3; k++) {
                const float4 wv = *(const float4*)(wp + (k * D + d + dd) * F);
                #pragma unroll
                for (int tt = 0; tt < TPW; tt++) {
                    const float rv = (dd == 0) ? r[tt + k].x
                                   : (dd == 1) ? r[tt + k].y
                                   : (dd == 2) ? r[tt + k].z
                                               : r[tt + k].w;
                    acc[tt][0] += rv * wv.x;
                    acc[tt][1] += rv * wv.y;
                    acc[tt][2] += rv * wv.z;
                    acc[tt][3] += rv * wv.w;
                }
            }
        }
    }

    const float4 cbv = *(const float4*)(cb + f0);
    const float4 gv  = *(const float4*)(gamma + f0);
    const float4 bv  = *(const float4*)(beta + f0);
    float4 lwv = make_float4(0.f, 0.f, 0.f, 0.f);
    float lbv = 0.f;
    if constexpr (DOT) { lwv = *(const float4*)(lw + f0); lbv = lb[0]; }

    #pragma unroll
    for (int tt = 0; tt < TPW; tt++) {
        const float v0 = fmaxf(acc[tt][0] + cbv.x, 0.f);
        const float v1 = fmaxf(acc[tt][1] + cbv.y, 0.f);
        const float v2 = fmaxf(acc[tt][2] + cbv.z, 0.f);
        const float v3 = fmaxf(acc[tt][3] + cbv.w, 0.f);
        float s = v0 + v1 + v2 + v3;
        float q = v0 * v0 + v1 * v1 + v2 * v2 + v3 * v3;
        #pragma unroll
        for (int off = 32; off; off >>= 1) {
            s += __shfl_xor(s, off);
            q += __shfl_xor(q, off);
        }
        const float m = s * (1.f / 256.f);
        float var = q * (1.f / 256.f) - m * m;
        var = fmaxf(var, 0.f);
        const float rs = rsqrtf(var + LN_EPS);
        const int t = t0 + g * TPW + tt;
        if constexpr (!DOT) {
            float4 o;
            o.x = (v0 - m) * rs * gv.x + bv.x;
            o.y = (v1 - m) * rs * gv.y + bv.y;
            o.z = (v2 - m) * rs * gv.z + bv.z;
            o.w = (v3 - m) * rs * gv.w + bv.w;
            *(float4*)(out + ((size_t)b * Tlen + t) * F + f0) = o;
        } else {
            float p = ((v0 - m) * rs * gv.x + bv.x) * lwv.x
                    + ((v1 - m) * rs * gv.y + bv.y) * lwv.y
                    + ((v2 - m) * rs * gv.z + bv.z) * lwv.z
                    + ((v3 - m) * rs * gv.w + bv.w) * lwv.w;
            #pragma unroll
            for (int off = 32; off; off >>= 1) p += __shfl_xor(p, off);
            if (lane == 0) out[(size_t)b * Tlen + t] = fmaxf(p + lbv, 0.f);
        }
    }
}

extern "C" void kernel_launch(void* const* d_in, const int* in_sizes, int n_in,
                              void* d_out, int out_size, void* d_ws, size_t ws_size,
                              hipStream_t stream) {
    const float* x        = (const float*)d_in[0];
    const int*   d_target = (const int*)d_in[1];
    const float* e_target = (const float*)d_in[2];
    const float* p_target = (const float*)d_in[3];
    // d_in[4] = mel_max_length (fixed T=2048)

    // predictor params: base 5 (dur), 15 (en), 25 (pi); order:
    // c1w, c1b, g1, b1, c2w, c2b, g2, b2, lw, lb
    const float* const* P = (const float* const*)d_in;
    const float* en_emb  = (const float*)d_in[35];
    const float* pi_emb  = (const float*)d_in[36];
    const float* en_bins = (const float*)d_in[37];
    const float* pi_bins = (const float*)d_in[38];

    float* out = (float*)d_out;
    float* h        = out;                                   // B*T*D
    float* log_dur  = out + (size_t)B * T * D;               // B*L
    float* pitch    = log_dur + (size_t)B * L;               // B*T
    float* energy   = pitch + (size_t)B * T;                 // B*T

    float* buf1 = (float*)d_ws;                              // B*T*F floats
    int*   cum  = (int*)((char*)d_ws + (size_t)B * T * F * sizeof(float));

    // 1. duration cumsum + length-regulate gather into h
    cumsum_kernel<<<B, L, 0, stream>>>(d_target, cum);
    lr_gather_kernel<<<B * T / 4, BDIM, 0, stream>>>(x, cum, h);

    // 2. duration predictor on x -> log_dur
    {
        const int base = 5;
        conv_ln_kernel<false><<<dim3(L / TILE_T, B), BDIM, 0, stream>>>(
            x, L, P[base + 0], P[base + 1], P[base + 2], P[base + 3],
            nullptr, nullptr, buf1);
        conv_ln_kernel<true><<<dim3(L / TILE_T, B), BDIM, 0, stream>>>(
            buf1, L, P[base + 4], P[base + 5], P[base + 6], P[base + 7],
            P[base + 8], P[base + 9], log_dur);
    }

    // 3. energy predictor on h -> energy; then h += en_emb[bucketize(e_target)]
    {
        const int base = 15;
        conv_ln_kernel<false><<<dim3(T / TILE_T, B), BDIM, 0, stream>>>(
            h, T, P[base + 0], P[base + 1], P[base + 2], P[base + 3],
            nullptr, nullptr, buf1);
        conv_ln_kernel<true><<<dim3(T / TILE_T, B), BDIM, 0, stream>>>(
            buf1, T, P[base + 4], P[base + 5], P[base + 6], P[base + 7],
            P[base + 8], P[base + 9], energy);
        add_emb_kernel<<<B * T / 4, BDIM, 0, stream>>>(e_target, en_bins, en_emb, h);
    }

    // 4. pitch predictor on h -> pitch; then h += pi_emb[bucketize(p_target)]
    {
        const int base = 25;
        conv_ln_kernel<false><<<dim3(T / TILE_T, B), BDIM, 0, stream>>>(
            h, T, P[base + 0], P[base + 1], P[base + 2], P[base + 3],
            nullptr, nullptr, buf1);
        conv_ln_kernel<true><<<dim3(T / TILE_T, B), BDIM, 0, stream>>>(
            buf1, T, P[base + 4], P[base + 5], P[base + 6], P[base + 7],
            P[base + 8], P[base + 9], pitch);
        add_emb_kernel<<<B * T / 4, BDIM, 0, stream>>>(p_target, pi_bins, pi_emb, h);
    }
}

// Round 2
// 313.698 us; speedup vs baseline: 5.0257x; 5.0257x over previous
//
#include <hip/hip_runtime.h>
#include <hip/hip_bf16.h>
#include <cstddef>

constexpr int B = 32, L = 512, D = 256, F = 256, T = 2048, NB = 256;
constexpr float LN_EPS = 1e-5f;
constexpr int BDIM = 256;

typedef __attribute__((ext_vector_type(8))) short short8;
typedef __attribute__((ext_vector_type(4))) float f32x4;

__device__ inline short f2bf(float x) {
    __hip_bfloat16 h = __float2bfloat16(x);
    return __builtin_bit_cast(short, h);
}

// ---------------- cumsum over durations (per batch row) ----------------
__global__ void cumsum_kernel(const int* __restrict__ dt, int* __restrict__ cum) {
    __shared__ int s[L];
    const int b = blockIdx.x, tid = threadIdx.x;
    s[tid] = dt[b * L + tid];
    __syncthreads();
    for (int off = 1; off < L; off <<= 1) {
        int v = (tid >= off) ? s[tid - off] : 0;
        __syncthreads();
        s[tid] += v;
        __syncthreads();
    }
    cum[b * L + tid] = s[tid];
}

// ---------------- length regulator gather: h[b,t,:] = x[b,idx,:] or 0 ----
__global__ void lr_gather_kernel(const float* __restrict__ x, const int* __restrict__ cum,
                                 float* __restrict__ h) {
    const int wave = threadIdx.x >> 6, lane = threadIdx.x & 63;
    const int row = blockIdx.x * 4 + wave;     // b*T + t
    const int b = row / T, t = row % T;
    const int* c = cum + b * L;
    int lo = 0, hi = L;
    while (lo < hi) { const int mid = (lo + hi) >> 1; if (c[mid] <= t) lo = mid + 1; else hi = mid; }
    float4 v = make_float4(0.f, 0.f, 0.f, 0.f);
    if (lo < L) v = *(const float4*)(x + ((size_t)b * L + lo) * D + lane * 4);
    *(float4*)(h + (size_t)row * D + lane * 4) = v;
}

// ---------------- h[b,t,:] += emb[bucketize(tgt[b,t]), :] ----------------
__global__ void add_emb_kernel(const float* __restrict__ tgt, const float* __restrict__ bins,
                               const float* __restrict__ emb, float* __restrict__ h) {
    const int wave = threadIdx.x >> 6, lane = threadIdx.x & 63;
    const int row = blockIdx.x * 4 + wave;     // b*T + t
    const float e = tgt[row];
    int lo = 0, hi = NB - 1;
    while (lo < hi) { const int mid = (lo + hi) >> 1; if (bins[mid] < e) lo = mid + 1; else hi = mid; }
    const size_t off = (size_t)row * D + lane * 4;
    float4 hv = *(float4*)(h + off);
    const float4 ev = *(const float4*)(emb + (size_t)lo * D + lane * 4);
    hv.x += ev.x; hv.y += ev.y; hv.z += ev.z; hv.w += ev.w;
    *(float4*)(h + off) = hv;
}

// -------- weight repack: W[3][256][256] fp32 -> MFMA B-fragments bf16 ----
// frag id phi in [0, 24*16*64): kb = phi/1024, n16 = (phi/64)&15, lane = phi&63
// wb[phi][j] = W[kconv][dblk*32 + kg*8 + j][n16*16 + (lane&15)]
__global__ void wprep_kernel(const float* __restrict__ w, short* __restrict__ wb) {
    const int phi = blockIdx.x * BDIM + threadIdx.x;   // 0..24575
    const int kb = phi >> 10;
    const int n16 = (phi >> 6) & 15;
    const int lane = phi & 63;
    const int kconv = kb >> 3, dblk = kb & 7;
    const int kg = lane >> 4, fcol = n16 * 16 + (lane & 15);
    const float* src = w + (size_t)kconv * D * F + (dblk * 32 + kg * 8) * F + fcol;
    short8 o;
    #pragma unroll
    for (int j = 0; j < 8; j++) o[j] = f2bf(src[j * F]);
    *(short8*)(wb + (size_t)phi * 8) = o;
}

// ------- fused conv1d(k=3,SAME) via MFMA + bias + ReLU + LayerNorm -------
// INBF:  input is bf16 (intermediate buffer) vs fp32 (x / h)
// DOT=false: write LN'd rows bf16 -> out [Tlen, F]
// DOT=true : LN + dot(lw) + lb + ReLU -> out fp32 [Tlen]
template <bool INBF, bool DOT>
__launch_bounds__(BDIM, 3)
__global__ void conv_mfma_kernel(const void* __restrict__ in_, int Tlen,
                                 const short* __restrict__ wb,
                                 const float* __restrict__ cb,
                                 const float* __restrict__ gamma,
                                 const float* __restrict__ beta,
                                 const float* __restrict__ lw,
                                 const float* __restrict__ lb,
                                 void* __restrict__ out_) {
    __shared__ short in_s[66 * 256];            // 33.8 KB, XOR-swizzled
    __shared__ float red_s[4][64], red_q[4][64];
    __shared__ float row_m[64], row_rs[64];
    __shared__ float dot_p[4][64];

    const int b = blockIdx.y;
    const int t0 = blockIdx.x * 64;
    const int tid = threadIdx.x;
    const int w = tid >> 6, lane = tid & 63;
    const int kg = lane >> 4, lr = lane & 15;

    // ---- stage rows t0-1 .. t0+64 as bf16, swizzle slot ^= row&7 ----
    for (int it = 0; it < 9; it++) {
        const int task = tid + it * BDIM;
        if (task < 66 * 32) {
            const int row = task >> 5, slot = task & 31;
            const int t = t0 - 1 + row;
            short8 frag = {};
            if (t >= 0 && t < Tlen) {
                if constexpr (INBF) {
                    frag = *(const short8*)((const short*)in_ + ((size_t)b * Tlen + t) * F + slot * 8);
                } else {
                    const float* p = (const float*)in_ + ((size_t)b * Tlen + t) * D + slot * 8;
                    const float4 v0 = *(const float4*)p, v1 = *(const float4*)(p + 4);
                    frag[0] = f2bf(v0.x); frag[1] = f2bf(v0.y); frag[2] = f2bf(v0.z); frag[3] = f2bf(v0.w);
                    frag[4] = f2bf(v1.x); frag[5] = f2bf(v1.y); frag[6] = f2bf(v1.z); frag[7] = f2bf(v1.w);
                }
            }
            *(short8*)(in_s + row * 256 + ((slot ^ (row & 7)) << 3)) = frag;
        }
    }
    __syncthreads();

    f32x4 acc[4][4];
    #pragma unroll
    for (int m = 0; m < 4; m++)
        #pragma unroll
        for (int n = 0; n < 4; n++)
            acc[m][n] = (f32x4){0.f, 0.f, 0.f, 0.f};

    const short8* bw = (const short8*)wb;
    for (int kb = 0; kb < 24; kb++) {
        const int kconv = kb >> 3, dblk = kb & 7;
        short8 bfr[4];
        #pragma unroll
        for (int n = 0; n < 4; n++)
            bfr[n] = bw[(kb * 16 + w * 4 + n) * 64 + lane];
        #pragma unroll
        for (int m = 0; m < 4; m++) {
            const int row = m * 16 + lr + kconv;
            const short8 a = *(const short8*)(in_s + row * 256 + (((dblk * 4 + kg) ^ (row & 7)) << 3));
            #pragma unroll
            for (int n = 0; n < 4; n++)
                acc[m][n] = __builtin_amdgcn_mfma_f32_16x16x32_bf16(a, bfr[n], acc[m][n], 0, 0, 0);
        }
    }

    // ---- epilogue: bias + ReLU + LayerNorm (+ optional dot) ----
    float cbv[4], gv[4], bvv[4], lwv[4];
    #pragma unroll
    for (int n = 0; n < 4; n++) {
        const int c = w * 64 + n * 16 + lr;
        cbv[n] = cb[c]; gv[n] = gamma[c]; bvv[n] = beta[c];
        lwv[n] = DOT ? lw[c] : 0.f;
    }

    #pragma unroll
    for (int m = 0; m < 4; m++) {
        #pragma unroll
        for (int reg = 0; reg < 4; reg++) {
            float s = 0.f, q = 0.f;
            #pragma unroll
            for (int n = 0; n < 4; n++) {
                const float v = fmaxf(acc[m][n][reg] + cbv[n], 0.f);
                acc[m][n][reg] = v;
                s += v; q += v * v;
            }
            #pragma unroll
            for (int msk = 1; msk < 16; msk <<= 1) { s += __shfl_xor(s, msk); q += __shfl_xor(q, msk); }
            if (lr == 0) {
                const int r = m * 16 + kg * 4 + reg;
                red_s[w][r] = s; red_q[w][r] = q;
            }
        }
    }
    __syncthreads();
    if (tid < 64) {
        const float s = red_s[0][tid] + red_s[1][tid] + red_s[2][tid] + red_s[3][tid];
        const float q = red_q[0][tid] + red_q[1][tid] + red_q[2][tid] + red_q[3][tid];
        const float mm = s * (1.f / 256.f);
        const float var = fmaxf(q * (1.f / 256.f) - mm * mm, 0.f);
        row_m[tid] = mm;
        row_rs[tid] = rsqrtf(var + LN_EPS);
    }
    __syncthreads();

    if constexpr (!DOT) {
        short* outb = (short*)out_;
        #pragma unroll
        for (int m = 0; m < 4; m++) {
            #pragma unroll
            for (int reg = 0; reg < 4; reg++) {
                const int r = m * 16 + kg * 4 + reg;
                const float mm = row_m[r], rs = row_rs[r];
                #pragma unroll
                for (int n = 0; n < 4; n++) {
                    const int c = w * 64 + n * 16 + lr;
                    outb[((size_t)b * Tlen + t0 + r) * F + c] =
                        f2bf((acc[m][n][reg] - mm) * rs * gv[n] + bvv[n]);
                }
            }
        }
    } else {
        #pragma unroll
        for (int m = 0; m < 4; m++) {
            #pragma unroll
            for (int reg = 0; reg < 4; reg++) {
                const int r = m * 16 + kg * 4 + reg;
                const float mm = row_m[r], rs = row_rs[r];
                float p = 0.f;
                #pragma unroll
                for (int n = 0; n < 4; n++)
                    p += ((acc[m][n][reg] - mm) * rs * gv[n] + bvv[n]) * lwv[n];
                #pragma unroll
                for (int msk = 1; msk < 16; msk <<= 1) p += __shfl_xor(p, msk);
                if (lr == 0) dot_p[w][r] = p;
            }
        }
        __syncthreads();
        if (tid < 64) {
            const float p = dot_p[0][tid] + dot_p[1][tid] + dot_p[2][tid] + dot_p[3][tid] + lb[0];
            ((float*)out_)[(size_t)b * Tlen + t0 + tid] = fmaxf(p, 0.f);
        }
    }
}

extern "C" void kernel_launch(void* const* d_in, const int* in_sizes, int n_in,
                              void* d_out, int out_size, void* d_ws, size_t ws_size,
                              hipStream_t stream) {
    const float* x        = (const float*)d_in[0];
    const int*   d_target = (const int*)d_in[1];
    const float* e_target = (const float*)d_in[2];
    const float* p_target = (const float*)d_in[3];

    const float* const* P = (const float* const*)d_in;
    const float* en_emb  = (const float*)d_in[35];
    const float* pi_emb  = (const float*)d_in[36];
    const float* en_bins = (const float*)d_in[37];
    const float* pi_bins = (const float*)d_in[38];

    float* out = (float*)d_out;
    float* h        = out;                                   // B*T*D
    float* log_dur  = out + (size_t)B * T * D;               // B*L
    float* pitch    = log_dur + (size_t)B * L;               // B*T
    float* energy   = pitch + (size_t)B * T;                 // B*T

    // workspace layout
    short* buf1 = (short*)d_ws;                              // B*T*F bf16 (33.5 MB)
    short* wbs  = buf1 + (size_t)B * T * F;                  // 6 * 196608 shorts
    int*   cum  = (int*)(wbs + 6 * 196608);

    constexpr int WFRAGS = 24 * 16 * 64;                     // 24576 frags/layer

    // repack all 6 conv weights to bf16 MFMA fragments
    const int wsrc[6] = {5, 9, 15, 19, 25, 29};
    for (int i = 0; i < 6; i++)
        wprep_kernel<<<WFRAGS / BDIM, BDIM, 0, stream>>>(P[wsrc[i]], wbs + (size_t)i * WFRAGS * 8);

    // 1. duration cumsum + length-regulate gather into h
    cumsum_kernel<<<B, L, 0, stream>>>(d_target, cum);
    lr_gather_kernel<<<B * T / 4, BDIM, 0, stream>>>(x, cum, h);

    // 2. duration predictor on x -> log_dur
    {
        const int base = 5;
        conv_mfma_kernel<false, false><<<dim3(L / 64, B), BDIM, 0, stream>>>(
            x, L, wbs + (size_t)0 * WFRAGS * 8,
            P[base + 1], P[base + 2], P[base + 3], nullptr, nullptr, buf1);
        conv_mfma_kernel<true, true><<<dim3(L / 64, B), BDIM, 0, stream>>>(
            buf1, L, wbs + (size_t)1 * WFRAGS * 8,
            P[base + 5], P[base + 6], P[base + 7], P[base + 8], P[base + 9], log_dur);
    }

    // 3. energy predictor on h -> energy; then h += en_emb[bucketize(e_target)]
    {
        const int base = 15;
        conv_mfma_kernel<false, false><<<dim3(T / 64, B), BDIM, 0, stream>>>(
            h, T, wbs + (size_t)2 * WFRAGS * 8,
            P[base + 1], P[base + 2], P[base + 3], nullptr, nullptr, buf1);
        conv_mfma_kernel<true, true><<<dim3(T / 64, B), BDIM, 0, stream>>>(
            buf1, T, wbs + (size_t)3 * WFRAGS * 8,
            P[base + 5], P[base + 6], P[base + 7], P[base + 8], P[base + 9], energy);
        add_emb_kernel<<<B * T / 4, BDIM, 0, stream>>>(e_target, en_bins, en_emb, h);
    }

    // 4. pitch predictor on h -> pitch; then h += pi_emb[bucketize(p_target)]
    {
        const int base = 25;
        conv_mfma_kernel<false, false><<<dim3(T / 64, B), BDIM, 0, stream>>>(
            h, T, wbs + (size_t)4 * WFRAGS * 8,
            P[base + 1], P[base + 2], P[base + 3], nullptr, nullptr, buf1);
        conv_mfma_kernel<true, true><<<dim3(T / 64, B), BDIM, 0, stream>>>(
            buf1, T, wbs + (size_t)5 * WFRAGS * 8,
            P[base + 5], P[base + 6], P[base + 7], P[base + 8], P[base + 9], pitch);
        add_emb_kernel<<<B * T / 4, BDIM, 0, stream>>>(p_target, pi_bins, pi_emb, h);
    }
}

// Round 3
// 311.442 us; speedup vs baseline: 5.0621x; 1.0072x over previous
//
#include <hip/hip_runtime.h>
#include <hip/hip_bf16.h>
#include <cstddef>

constexpr int B = 32, L = 512, D = 256, F = 256, T = 2048, NB = 256;
constexpr float LN_EPS = 1e-5f;
constexpr int BDIM = 256;
constexpr int TM = 128;                 // output rows per conv block

typedef __attribute__((ext_vector_type(8))) short short8;
typedef __attribute__((ext_vector_type(4))) short short4v;
typedef __attribute__((ext_vector_type(4))) float f32x4;

__device__ inline short f2bf(float x) {
    __hip_bfloat16 h = __float2bfloat16(x);
    return __builtin_bit_cast(short, h);
}
__device__ inline float bf2f(short s) {
    unsigned u = ((unsigned)(unsigned short)s) << 16;
    return __builtin_bit_cast(float, u);
}

// ---------------- cumsum over durations (per batch row) ----------------
__global__ void cumsum_kernel(const int* __restrict__ dt, int* __restrict__ cum) {
    __shared__ int s[L];
    const int b = blockIdx.x, tid = threadIdx.x;
    s[tid] = dt[b * L + tid];
    __syncthreads();
    for (int off = 1; off < L; off <<= 1) {
        int v = (tid >= off) ? s[tid - off] : 0;
        __syncthreads();
        s[tid] += v;
        __syncthreads();
    }
    cum[b * L + tid] = s[tid];
}

// ---------------- bucketize: idx[i] = searchsorted(bins, tgt[i], left) ---
__global__ void bucket_kernel(const float* __restrict__ tgt, const float* __restrict__ bins,
                              int* __restrict__ idx, int n) {
    const int i = blockIdx.x * BDIM + threadIdx.x;
    if (i >= n) return;
    const float e = tgt[i];
    int lo = 0, hi = NB - 1;
    while (lo < hi) { const int mid = (lo + hi) >> 1; if (bins[mid] < e) lo = mid + 1; else hi = mid; }
    idx[i] = lo;
}

// -------- gather to bf16: hbf[b,t,:] = bf16(x[b,idx,:]) or 0 -------------
__global__ void gather_bf_kernel(const float* __restrict__ x, const int* __restrict__ cum,
                                 short* __restrict__ hbf) {
    const int wave = threadIdx.x >> 6, lane = threadIdx.x & 63;
    const int row = blockIdx.x * 4 + wave;     // b*T + t
    const int b = row / T, t = row % T;
    const int* c = cum + b * L;
    int lo = 0, hi = L;
    while (lo < hi) { const int mid = (lo + hi) >> 1; if (c[mid] <= t) lo = mid + 1; else hi = mid; }
    float4 v = make_float4(0.f, 0.f, 0.f, 0.f);
    if (lo < L) v = *(const float4*)(x + ((size_t)b * L + lo) * D + lane * 4);
    short4v o;
    o[0] = f2bf(v.x); o[1] = f2bf(v.y); o[2] = f2bf(v.z); o[3] = f2bf(v.w);
    *(short4v*)(hbf + (size_t)row * D + lane * 4) = o;
}

// -------- final h: gather(x) + en_emb[e_idx] + pi_emb[p_idx], fp32 -------
__global__ void final_h_kernel(const float* __restrict__ x, const int* __restrict__ cum,
                               const float* __restrict__ et, const float* __restrict__ ebins,
                               const float* __restrict__ eemb,
                               const float* __restrict__ pt, const float* __restrict__ pbins,
                               const float* __restrict__ pemb,
                               float* __restrict__ h) {
    const int wave = threadIdx.x >> 6, lane = threadIdx.x & 63;
    const int row = blockIdx.x * 4 + wave;     // b*T + t
    const int b = row / T, t = row % T;
    const int* c = cum + b * L;
    int lo = 0, hi = L;
    while (lo < hi) { const int mid = (lo + hi) >> 1; if (c[mid] <= t) lo = mid + 1; else hi = mid; }
    const float e = et[row];
    int el = 0, eh = NB - 1;
    while (el < eh) { const int mid = (el + eh) >> 1; if (ebins[mid] < e) el = mid + 1; else eh = mid; }
    const float p = pt[row];
    int pl = 0, ph = NB - 1;
    while (pl < ph) { const int mid = (pl + ph) >> 1; if (pbins[mid] < p) pl = mid + 1; else ph = mid; }
    float4 v = make_float4(0.f, 0.f, 0.f, 0.f);
    if (lo < L) v = *(const float4*)(x + ((size_t)b * L + lo) * D + lane * 4);
    const float4 ev = *(const float4*)(eemb + (size_t)el * D + lane * 4);
    const float4 pv = *(const float4*)(pemb + (size_t)pl * D + lane * 4);
    v.x += ev.x + pv.x; v.y += ev.y + pv.y; v.z += ev.z + pv.z; v.w += ev.w + pv.w;
    *(float4*)(h + (size_t)row * D + lane * 4) = v;
}

// -------- weight repack: W[3][256][256] fp32 -> MFMA B-fragments bf16 ----
__global__ void wprep_kernel(const float* __restrict__ w, short* __restrict__ wb) {
    const int phi = blockIdx.x * BDIM + threadIdx.x;   // 0..24575
    const int kb = phi >> 10;
    const int n16 = (phi >> 6) & 15;
    const int lane = phi & 63;
    const int kconv = kb >> 3, dblk = kb & 7;
    const int kg = lane >> 4, fcol = n16 * 16 + (lane & 15);
    const float* src = w + (size_t)kconv * D * F + (dblk * 32 + kg * 8) * F + fcol;
    short8 o;
    #pragma unroll
    for (int j = 0; j < 8; j++) o[j] = f2bf(src[j * F]);
    *(short8*)(wb + (size_t)phi * 8) = o;
}

// ------- fused conv1d(k=3,SAME) via MFMA + bias + ReLU + LayerNorm -------
// INBF: input bf16 vs fp32; EMB: add emb[eidx[t]] (fp32) during staging
// DOT=false: write LN rows bf16; DOT=true: LN+dot(lw)+lb+ReLU -> fp32 [Tlen]
template <bool INBF, bool DOT, bool EMB>
__launch_bounds__(BDIM, 2)
__global__ void conv_mfma_kernel(const void* __restrict__ in_, int Tlen,
                                 const short* __restrict__ wb,
                                 const float* __restrict__ cb,
                                 const float* __restrict__ gamma,
                                 const float* __restrict__ beta,
                                 const float* __restrict__ lw,
                                 const float* __restrict__ lb,
                                 const int* __restrict__ eidx,
                                 const float* __restrict__ emb,
                                 void* __restrict__ out_) {
    __shared__ short in_s[(TM + 2) * 256];      // 66.6 KB, XOR-swizzled
    __shared__ float red_s[4][TM], red_q[4][TM];
    __shared__ float row_m[TM], row_rs[TM];
    __shared__ float dot_p[4][TM];

    const int b = blockIdx.y;
    const int t0 = blockIdx.x * TM;
    const int tid = threadIdx.x;
    const int w = tid >> 6, lane = tid & 63;
    const int kg = lane >> 4, lr = lane & 15;

    // ---- stage rows t0-1 .. t0+TM as bf16, swizzle slot ^= row&7 ----
    #pragma unroll 1
    for (int it = 0; it < 17; it++) {
        const int task = tid + it * BDIM;
        if (task < (TM + 2) * 32) {
            const int row = task >> 5, slot = task & 31;
            const int t = t0 - 1 + row;
            short8 frag = {};
            if (t >= 0 && t < Tlen) {
                if constexpr (INBF) {
                    frag = *(const short8*)((const short*)in_ + ((size_t)b * Tlen + t) * F + slot * 8);
                    if constexpr (EMB) {
                        const float* er = emb + (size_t)eidx[b * Tlen + t] * F + slot * 8;
                        #pragma unroll
                        for (int j = 0; j < 8; j++) frag[j] = f2bf(bf2f(frag[j]) + er[j]);
                    }
                } else {
                    const float* p = (const float*)in_ + ((size_t)b * Tlen + t) * D + slot * 8;
                    const float4 v0 = *(const float4*)p, v1 = *(const float4*)(p + 4);
                    frag[0] = f2bf(v0.x); frag[1] = f2bf(v0.y); frag[2] = f2bf(v0.z); frag[3] = f2bf(v0.w);
                    frag[4] = f2bf(v1.x); frag[5] = f2bf(v1.y); frag[6] = f2bf(v1.z); frag[7] = f2bf(v1.w);
                }
            }
            *(short8*)(in_s + row * 256 + ((slot ^ (row & 7)) << 3)) = frag;
        }
    }
    __syncthreads();

    f32x4 acc[8][4];
    #pragma unroll
    for (int m = 0; m < 8; m++)
        #pragma unroll
        for (int n = 0; n < 4; n++)
            acc[m][n] = (f32x4){0.f, 0.f, 0.f, 0.f};

    const short8* bw = (const short8*)wb;
    short8 bnext[4];
    #pragma unroll
    for (int n = 0; n < 4; n++) bnext[n] = bw[(w * 4 + n) * 64 + lane];

    #pragma unroll 1
    for (int kb = 0; kb < 24; kb++) {
        const int kconv = kb >> 3, dblk = kb & 7;
        short8 bcur[4];
        #pragma unroll
        for (int n = 0; n < 4; n++) bcur[n] = bnext[n];
        if (kb < 23) {
            #pragma unroll
            for (int n = 0; n < 4; n++) bnext[n] = bw[((kb + 1) * 16 + w * 4 + n) * 64 + lane];
        }
        #pragma unroll
        for (int m = 0; m < 8; m++) {
            const int row = m * 16 + lr + kconv;
            const short8 a = *(const short8*)(in_s + row * 256 + (((dblk * 4 + kg) ^ (row & 7)) << 3));
            #pragma unroll
            for (int n = 0; n < 4; n++)
                acc[m][n] = __builtin_amdgcn_mfma_f32_16x16x32_bf16(a, bcur[n], acc[m][n], 0, 0, 0);
        }
    }

    // ---- epilogue: bias + ReLU + LayerNorm (+ optional dot) ----
    float cbv[4], gv[4], bvv[4], lwv[4];
    #pragma unroll
    for (int n = 0; n < 4; n++) {
        const int c = w * 64 + n * 16 + lr;
        cbv[n] = cb[c]; gv[n] = gamma[c]; bvv[n] = beta[c];
        lwv[n] = DOT ? lw[c] : 0.f;
    }

    #pragma unroll
    for (int m = 0; m < 8; m++) {
        #pragma unroll
        for (int reg = 0; reg < 4; reg++) {
            float s = 0.f, q = 0.f;
            #pragma unroll
            for (int n = 0; n < 4; n++) {
                const float v = fmaxf(acc[m][n][reg] + cbv[n], 0.f);
                acc[m][n][reg] = v;
                s += v; q += v * v;
            }
            #pragma unroll
            for (int msk = 1; msk < 16; msk <<= 1) { s += __shfl_xor(s, msk); q += __shfl_xor(q, msk); }
            if (lr == 0) {
                const int r = m * 16 + kg * 4 + reg;
                red_s[w][r] = s; red_q[w][r] = q;
            }
        }
    }
    __syncthreads();
    if (tid < TM) {
        const float s = red_s[0][tid] + red_s[1][tid] + red_s[2][tid] + red_s[3][tid];
        const float q = red_q[0][tid] + red_q[1][tid] + red_q[2][tid] + red_q[3][tid];
        const float mm = s * (1.f / 256.f);
        const float var = fmaxf(q * (1.f / 256.f) - mm * mm, 0.f);
        row_m[tid] = mm;
        row_rs[tid] = rsqrtf(var + LN_EPS);
    }
    __syncthreads();

    if constexpr (!DOT) {
        short* outb = (short*)out_;
        #pragma unroll
        for (int m = 0; m < 8; m++) {
            #pragma unroll
            for (int reg = 0; reg < 4; reg++) {
                const int r = m * 16 + kg * 4 + reg;
                const float mm = row_m[r], rs = row_rs[r];
                #pragma unroll
                for (int n = 0; n < 4; n++) {
                    const int c = w * 64 + n * 16 + lr;
                    outb[((size_t)b * Tlen + t0 + r) * F + c] =
                        f2bf((acc[m][n][reg] - mm) * rs * gv[n] + bvv[n]);
                }
            }
        }
    } else {
        #pragma unroll
        for (int m = 0; m < 8; m++) {
            #pragma unroll
            for (int reg = 0; reg < 4; reg++) {
                const int r = m * 16 + kg * 4 + reg;
                const float mm = row_m[r], rs = row_rs[r];
                float p = 0.f;
                #pragma unroll
                for (int n = 0; n < 4; n++)
                    p += ((acc[m][n][reg] - mm) * rs * gv[n] + bvv[n]) * lwv[n];
                #pragma unroll
                for (int msk = 1; msk < 16; msk <<= 1) p += __shfl_xor(p, msk);
                if (lr == 0) dot_p[w][r] = p;
            }
        }
        __syncthreads();
        if (tid < TM) {
            const float p = dot_p[0][tid] + dot_p[1][tid] + dot_p[2][tid] + dot_p[3][tid] + lb[0];
            ((float*)out_)[(size_t)b * Tlen + t0 + tid] = fmaxf(p, 0.f);
        }
    }
}

extern "C" void kernel_launch(void* const* d_in, const int* in_sizes, int n_in,
                              void* d_out, int out_size, void* d_ws, size_t ws_size,
                              hipStream_t stream) {
    const float* x        = (const float*)d_in[0];
    const int*   d_target = (const int*)d_in[1];
    const float* e_target = (const float*)d_in[2];
    const float* p_target = (const float*)d_in[3];

    const float* const* P = (const float* const*)d_in;
    const float* en_emb  = (const float*)d_in[35];
    const float* pi_emb  = (const float*)d_in[36];
    const float* en_bins = (const float*)d_in[37];
    const float* pi_bins = (const float*)d_in[38];

    float* out = (float*)d_out;
    float* h        = out;                                   // B*T*D fp32
    float* log_dur  = out + (size_t)B * T * D;               // B*L
    float* pitch    = log_dur + (size_t)B * L;               // B*T
    float* energy   = pitch + (size_t)B * T;                 // B*T

    // workspace layout
    short* buf1 = (short*)d_ws;                              // B*T*F bf16
    short* wbs  = buf1 + (size_t)B * T * F;                  // 6 * 196608 shorts
    int*   cum  = (int*)(wbs + 6 * 196608);                  // B*L
    int*   eidx = cum + B * L;                               // B*T
    // hbf (bf16 gather result) lives in the h output region until final_h
    short* hbf  = (short*)d_out;

    constexpr int WFRAGS = 24 * 16 * 64;

    // repack all 6 conv weights to bf16 MFMA fragments
    const int wsrc[6] = {5, 9, 15, 19, 25, 29};
    for (int i = 0; i < 6; i++)
        wprep_kernel<<<WFRAGS / BDIM, BDIM, 0, stream>>>(P[wsrc[i]], wbs + (size_t)i * WFRAGS * 8);

    cumsum_kernel<<<B, L, 0, stream>>>(d_target, cum);
    bucket_kernel<<<(B * T + BDIM - 1) / BDIM, BDIM, 0, stream>>>(e_target, en_bins, eidx, B * T);
    gather_bf_kernel<<<B * T / 4, BDIM, 0, stream>>>(x, cum, hbf);

    // duration predictor on x -> log_dur
    conv_mfma_kernel<false, false, false><<<dim3(L / TM, B), BDIM, 0, stream>>>(
        x, L, wbs + (size_t)0 * WFRAGS * 8,
        P[6], P[7], P[8], nullptr, nullptr, nullptr, nullptr, buf1);
    conv_mfma_kernel<true, true, false><<<dim3(L / TM, B), BDIM, 0, stream>>>(
        buf1, L, wbs + (size_t)1 * WFRAGS * 8,
        P[10], P[11], P[12], P[13], P[14], nullptr, nullptr, log_dur);

    // energy predictor on hbf -> energy
    conv_mfma_kernel<true, false, false><<<dim3(T / TM, B), BDIM, 0, stream>>>(
        hbf, T, wbs + (size_t)2 * WFRAGS * 8,
        P[16], P[17], P[18], nullptr, nullptr, nullptr, nullptr, buf1);
    conv_mfma_kernel<true, true, false><<<dim3(T / TM, B), BDIM, 0, stream>>>(
        buf1, T, wbs + (size_t)3 * WFRAGS * 8,
        P[20], P[21], P[22], P[23], P[24], nullptr, nullptr, energy);

    // pitch predictor on (hbf + en_emb[eidx]) -> pitch
    conv_mfma_kernel<true, false, true><<<dim3(T / TM, B), BDIM, 0, stream>>>(
        hbf, T, wbs + (size_t)4 * WFRAGS * 8,
        P[26], P[27], P[28], nullptr, nullptr, eidx, en_emb, buf1);
    conv_mfma_kernel<true, true, false><<<dim3(T / TM, B), BDIM, 0, stream>>>(
        buf1, T, wbs + (size_t)5 * WFRAGS * 8,
        P[30], P[31], P[32], P[33], P[34], nullptr, nullptr, pitch);

    // final h = gather(x) + en_emb + pi_emb (fp32), overwrites hbf region
    final_h_kernel<<<B * T / 4, BDIM, 0, stream>>>(
        x, cum, e_target, en_bins, en_emb, p_target, pi_bins, pi_emb, h);
}

// Round 4
// 227.133 us; speedup vs baseline: 6.9411x; 1.3712x over previous
//
#include <hip/hip_runtime.h>
#include <hip/hip_bf16.h>
#include <cstddef>

constexpr int B = 32, L = 512, D = 256, F = 256, T = 2048, NB = 256;
constexpr float LN_EPS = 1e-5f;
constexpr int BDIM = 256;
constexpr int WFRAGS = 24 * 16 * 64;     // MFMA B-fragments per conv layer

typedef __attribute__((ext_vector_type(8))) short short8;
typedef __attribute__((ext_vector_type(4))) float f32x4;

__device__ inline short f2bf(float x) {
    __hip_bfloat16 h = __float2bfloat16(x);
    return __builtin_bit_cast(short, h);
}

// ---------------- cumsum over durations (per batch row) ----------------
__global__ void cumsum_kernel(const int* __restrict__ dt, int* __restrict__ cum) {
    __shared__ int s[L];
    const int b = blockIdx.x, tid = threadIdx.x;
    s[tid] = dt[b * L + tid];
    __syncthreads();
    for (int off = 1; off < L; off <<= 1) {
        int v = (tid >= off) ? s[tid - off] : 0;
        __syncthreads();
        s[tid] += v;
        __syncthreads();
    }
    cum[b * L + tid] = s[tid];
}

// ------- all index precompute: gidx (LR gather), eidx, pidx (buckets) ----
__global__ void idx_kernel(const int* __restrict__ cum,
                           const float* __restrict__ et, const float* __restrict__ ebins,
                           const float* __restrict__ pt, const float* __restrict__ pbins,
                           int* __restrict__ gidx, int* __restrict__ eidx, int* __restrict__ pidx) {
    const int r = blockIdx.x * BDIM + threadIdx.x;       // r < B*T
    const int b = r >> 11, t = r & (T - 1);
    const int* c = cum + b * L;
    int lo = 0, hi = L;
    while (lo < hi) { const int mid = (lo + hi) >> 1; if (c[mid] <= t) lo = mid + 1; else hi = mid; }
    gidx[r] = (lo < L) ? lo : -1;
    const float e = et[r];
    int el = 0, eh = NB - 1;
    while (el < eh) { const int mid = (el + eh) >> 1; if (ebins[mid] < e) el = mid + 1; else eh = mid; }
    eidx[r] = el;
    const float p = pt[r];
    int pl = 0, ph = NB - 1;
    while (pl < ph) { const int mid = (pl + ph) >> 1; if (pbins[mid] < p) pl = mid + 1; else ph = mid; }
    pidx[r] = pl;
}

// -------- final h: x[gidx] + en_emb[eidx] + pi_emb[pidx], pure stream ----
__global__ void final_h_kernel(const float* __restrict__ x, const int* __restrict__ gidx,
                               const int* __restrict__ eidx, const int* __restrict__ pidx,
                               const float* __restrict__ eemb, const float* __restrict__ pemb,
                               float* __restrict__ h) {
    const int wave = threadIdx.x >> 6, lane = threadIdx.x & 63;
    const int row = blockIdx.x * 4 + wave;               // b*T + t
    const int b = row >> 11;
    const int g = gidx[row], ei = eidx[row], pi = pidx[row];
    float4 v = make_float4(0.f, 0.f, 0.f, 0.f);
    if (g >= 0) v = *(const float4*)(x + ((size_t)b * L + g) * D + lane * 4);
    const float4 ev = *(const float4*)(eemb + (size_t)ei * D + lane * 4);
    const float4 pv = *(const float4*)(pemb + (size_t)pi * D + lane * 4);
    v.x += ev.x + pv.x; v.y += ev.y + pv.y; v.z += ev.z + pv.z; v.w += ev.w + pv.w;
    *(float4*)(h + (size_t)row * D + lane * 4) = v;
}

// -------- weight repack (all 6 layers, one launch) -----------------------
__global__ void wprep_kernel(const float* __restrict__ w0, const float* __restrict__ w1,
                             const float* __restrict__ w2, const float* __restrict__ w3,
                             const float* __restrict__ w4, const float* __restrict__ w5,
                             short* __restrict__ wb) {
    const float* ws[6] = {w0, w1, w2, w3, w4, w5};
    const float* w = ws[blockIdx.y];
    short* dst = wb + (size_t)blockIdx.y * WFRAGS * 8;
    const int phi = blockIdx.x * BDIM + threadIdx.x;     // 0..24575
    const int kb = phi >> 10;
    const int n16 = (phi >> 6) & 15;
    const int lane = phi & 63;
    const int kconv = kb >> 3, dblk = kb & 7;
    const int kg = lane >> 4, fcol = n16 * 16 + (lane & 15);
    const float* src = w + (size_t)kconv * D * F + (dblk * 32 + kg * 8) * F + fcol;
    short8 o;
    #pragma unroll
    for (int j = 0; j < 8; j++) o[j] = f2bf(src[j * F]);
    *(short8*)(dst + (size_t)phi * 8) = o;
}

// ------- fused conv1d(k=3,SAME) via MFMA + bias + ReLU + LayerNorm -------
// MODE 0: fp32 input rows (in = x or any [Tlen][256] fp32)
// MODE 1: bf16 input rows (intermediate buffer)
// MODE 2: gather fp32: row t <- x[b, gidx[b*T+t], :] (zero if -1)
// MODE 3: gather + en_emb[eidx[b*T+t]] added (fp32)
// DOT=false: write LN rows bf16; DOT=true: LN+dot(lw)+lb+ReLU -> fp32 [Tlen]
template <int TM, int MODE, bool DOT>
__launch_bounds__(BDIM, 2)
__global__ void conv_mfma_kernel(const void* __restrict__ in_, int Tlen,
                                 const int* __restrict__ gidx, const int* __restrict__ eidx,
                                 const float* __restrict__ emb,
                                 const short* __restrict__ wb,
                                 const float* __restrict__ cb,
                                 const float* __restrict__ gamma,
                                 const float* __restrict__ beta,
                                 const float* __restrict__ lw,
                                 const float* __restrict__ lb,
                                 void* __restrict__ out_) {
    constexpr int MROWS = TM / 16;
    constexpr int TASKS = (TM + 2) * 32;
    constexpr int ITERS = (TASKS + BDIM - 1) / BDIM;
    constexpr int BATCH = (MODE == 3) ? 2 : 4;

    __shared__ short in_s[(TM + 2) * 256];
    __shared__ float red_s[4][TM], red_q[4][TM];
    __shared__ float row_m[TM], row_rs[TM];
    __shared__ float dot_p[4][TM];

    const int b = blockIdx.y;
    const int t0 = blockIdx.x * TM;
    const int tid = threadIdx.x;
    const int w = tid >> 6, lane = tid & 63;
    const int kg = lane >> 4, lr = lane & 15;

    // issue first B-fragment prefetch BEFORE staging (hide L2 latency)
    const short8* bw = (const short8*)wb;
    short8 bnext[4];
    #pragma unroll
    for (int n = 0; n < 4; n++) bnext[n] = bw[(w * 4 + n) * 64 + lane];

    // ---- batched-pipelined staging: rows t0-1 .. t0+TM, swizzle ^row&7 ---
    for (int base = 0; base < ITERS; base += BATCH) {
        short8 vb[BATCH];                      // bf16 payloads (MODE 1)
        float4 fa[BATCH], fb[BATCH];           // fp32 payloads (MODE 0/2/3)
        float4 ea[BATCH], eb[BATCH];           // emb payloads  (MODE 3)
        #pragma unroll
        for (int j = 0; j < BATCH; j++) {
            const int task = tid + (base + j) * BDIM;
            vb[j] = short8{};
            fa[j] = make_float4(0.f, 0.f, 0.f, 0.f); fb[j] = fa[j];
            ea[j] = fa[j]; eb[j] = fa[j];
            if (task < TASKS) {
                const int row = task >> 5, slot = task & 31;
                const int t = t0 - 1 + row;
                if (t >= 0 && t < Tlen) {
                    if constexpr (MODE == 1) {
                        vb[j] = *(const short8*)((const short*)in_ + ((size_t)b * Tlen + t) * F + slot * 8);
                    } else if constexpr (MODE == 0) {
                        const float* p = (const float*)in_ + ((size_t)b * Tlen + t) * D + slot * 8;
                        fa[j] = *(const float4*)p; fb[j] = *(const float4*)(p + 4);
                    } else {
                        const int g = gidx[b * T + t];
                        if (g >= 0) {
                            const float* p = (const float*)in_ + ((size_t)b * L + g) * D + slot * 8;
                            fa[j] = *(const float4*)p; fb[j] = *(const float4*)(p + 4);
                        }
                        if constexpr (MODE == 3) {
                            const float* er = emb + (size_t)eidx[b * T + t] * F + slot * 8;
                            ea[j] = *(const float4*)er; eb[j] = *(const float4*)(er + 4);
                        }
                    }
                }
            }
        }
        #pragma unroll
        for (int j = 0; j < BATCH; j++) {
            const int task = tid + (base + j) * BDIM;
            if (task < TASKS) {
                const int row = task >> 5, slot = task & 31;
                short8 frag;
                if constexpr (MODE == 1) {
                    frag = vb[j];
                } else {
                    frag[0] = f2bf(fa[j].x + ea[j].x); frag[1] = f2bf(fa[j].y + ea[j].y);
                    frag[2] = f2bf(fa[j].z + ea[j].z); frag[3] = f2bf(fa[j].w + ea[j].w);
                    frag[4] = f2bf(fb[j].x + eb[j].x); frag[5] = f2bf(fb[j].y + eb[j].y);
                    frag[6] = f2bf(fb[j].z + eb[j].z); frag[7] = f2bf(fb[j].w + eb[j].w);
                }
                *(short8*)(in_s + row * 256 + ((slot ^ (row & 7)) << 3)) = frag;
            }
        }
    }
    __syncthreads();

    f32x4 acc[MROWS][4];
    #pragma unroll
    for (int m = 0; m < MROWS; m++)
        #pragma unroll
        for (int n = 0; n < 4; n++)
            acc[m][n] = (f32x4){0.f, 0.f, 0.f, 0.f};

    #pragma unroll 1
    for (int kb = 0; kb < 24; kb++) {
        const int kconv = kb >> 3, dblk = kb & 7;
        short8 bcur[4];
        #pragma unroll
        for (int n = 0; n < 4; n++) bcur[n] = bnext[n];
        if (kb < 23) {
            #pragma unroll
            for (int n = 0; n < 4; n++) bnext[n] = bw[((kb + 1) * 16 + w * 4 + n) * 64 + lane];
        }
        __builtin_amdgcn_s_setprio(1);
        #pragma unroll
        for (int m = 0; m < MROWS; m++) {
            const int row = m * 16 + lr + kconv;
            const short8 a = *(const short8*)(in_s + row * 256 + (((dblk * 4 + kg) ^ (row & 7)) << 3));
            #pragma unroll
            for (int n = 0; n < 4; n++)
                acc[m][n] = __builtin_amdgcn_mfma_f32_16x16x32_bf16(a, bcur[n], acc[m][n], 0, 0, 0);
        }
        __builtin_amdgcn_s_setprio(0);
    }

    // ---- epilogue: bias + ReLU + LayerNorm (+ optional dot) ----
    float cbv[4], gv[4], bvv[4], lwv[4];
    #pragma unroll
    for (int n = 0; n < 4; n++) {
        const int c = w * 64 + n * 16 + lr;
        cbv[n] = cb[c]; gv[n] = gamma[c]; bvv[n] = beta[c];
        lwv[n] = DOT ? lw[c] : 0.f;
    }

    #pragma unroll
    for (int m = 0; m < MROWS; m++) {
        #pragma unroll
        for (int reg = 0; reg < 4; reg++) {
            float s = 0.f, q = 0.f;
            #pragma unroll
            for (int n = 0; n < 4; n++) {
                const float v = fmaxf(acc[m][n][reg] + cbv[n], 0.f);
                acc[m][n][reg] = v;
                s += v; q += v * v;
            }
            #pragma unroll
            for (int msk = 1; msk < 16; msk <<= 1) { s += __shfl_xor(s, msk); q += __shfl_xor(q, msk); }
            if (lr == 0) {
                const int r = m * 16 + kg * 4 + reg;
                red_s[w][r] = s; red_q[w][r] = q;
            }
        }
    }
    __syncthreads();
    if (tid < TM) {
        const float s = red_s[0][tid] + red_s[1][tid] + red_s[2][tid] + red_s[3][tid];
        const float q = red_q[0][tid] + red_q[1][tid] + red_q[2][tid] + red_q[3][tid];
        const float mm = s * (1.f / 256.f);
        const float var = fmaxf(q * (1.f / 256.f) - mm * mm, 0.f);
        row_m[tid] = mm;
        row_rs[tid] = rsqrtf(var + LN_EPS);
    }
    __syncthreads();

    if constexpr (!DOT) {
        short* outb = (short*)out_;
        #pragma unroll
        for (int m = 0; m < MROWS; m++) {
            #pragma unroll
            for (int reg = 0; reg < 4; reg++) {
                const int r = m * 16 + kg * 4 + reg;
                const float mm = row_m[r], rs = row_rs[r];
                #pragma unroll
                for (int n = 0; n < 4; n++) {
                    const int c = w * 64 + n * 16 + lr;
                    outb[((size_t)b * Tlen + t0 + r) * F + c] =
                        f2bf((acc[m][n][reg] - mm) * rs * gv[n] + bvv[n]);
                }
            }
        }
    } else {
        #pragma unroll
        for (int m = 0; m < MROWS; m++) {
            #pragma unroll
            for (int reg = 0; reg < 4; reg++) {
                const int r = m * 16 + kg * 4 + reg;
                const float mm = row_m[r], rs = row_rs[r];
                float p = 0.f;
                #pragma unroll
                for (int n = 0; n < 4; n++)
                    p += ((acc[m][n][reg] - mm) * rs * gv[n] + bvv[n]) * lwv[n];
                #pragma unroll
                for (int msk = 1; msk < 16; msk <<= 1) p += __shfl_xor(p, msk);
                if (lr == 0) dot_p[w][r] = p;
            }
        }
        __syncthreads();
        if (tid < TM) {
            const float p = dot_p[0][tid] + dot_p[1][tid] + dot_p[2][tid] + dot_p[3][tid] + lb[0];
            ((float*)out_)[(size_t)b * Tlen + t0 + tid] = fmaxf(p, 0.f);
        }
    }
}

extern "C" void kernel_launch(void* const* d_in, const int* in_sizes, int n_in,
                              void* d_out, int out_size, void* d_ws, size_t ws_size,
                              hipStream_t stream) {
    const float* x        = (const float*)d_in[0];
    const int*   d_target = (const int*)d_in[1];
    const float* e_target = (const float*)d_in[2];
    const float* p_target = (const float*)d_in[3];

    const float* const* P = (const float* const*)d_in;
    const float* en_emb  = (const float*)d_in[35];
    const float* pi_emb  = (const float*)d_in[36];
    const float* en_bins = (const float*)d_in[37];
    const float* pi_bins = (const float*)d_in[38];

    float* out = (float*)d_out;
    float* h        = out;                                   // B*T*D fp32
    float* log_dur  = out + (size_t)B * T * D;               // B*L
    float* pitch    = log_dur + (size_t)B * L;               // B*T
    float* energy   = pitch + (size_t)B * T;                 // B*T

    // workspace layout
    short* buf1 = (short*)d_ws;                              // B*T*F bf16
    short* wbs  = buf1 + (size_t)B * T * F;                  // 6 * WFRAGS * 8 shorts
    int*   cum  = (int*)(wbs + (size_t)6 * WFRAGS * 8);      // B*L
    int*   gidx = cum + B * L;                               // B*T
    int*   eidx = gidx + B * T;                               // B*T
    int*   pidx = eidx + B * T;                               // B*T

    // weight repack (single launch, 6 layers)
    wprep_kernel<<<dim3(WFRAGS / BDIM, 6), BDIM, 0, stream>>>(
        P[5], P[9], P[15], P[19], P[25], P[29], wbs);

    cumsum_kernel<<<B, L, 0, stream>>>(d_target, cum);
    idx_kernel<<<B * T / BDIM, BDIM, 0, stream>>>(
        cum, e_target, en_bins, p_target, pi_bins, gidx, eidx, pidx);

    // duration predictor on x -> log_dur (TM=64: full-CU grid at L=512)
    conv_mfma_kernel<64, 0, false><<<dim3(L / 64, B), BDIM, 0, stream>>>(
        x, L, nullptr, nullptr, nullptr, wbs + (size_t)0 * WFRAGS * 8,
        P[6], P[7], P[8], nullptr, nullptr, buf1);
    conv_mfma_kernel<64, 1, true><<<dim3(L / 64, B), BDIM, 0, stream>>>(
        buf1, L, nullptr, nullptr, nullptr, wbs + (size_t)1 * WFRAGS * 8,
        P[10], P[11], P[12], P[13], P[14], log_dur);

    // energy predictor on gather(x) -> energy
    conv_mfma_kernel<128, 2, false><<<dim3(T / 128, B), BDIM, 0, stream>>>(
        x, T, gidx, nullptr, nullptr, wbs + (size_t)2 * WFRAGS * 8,
        P[16], P[17], P[18], nullptr, nullptr, buf1);
    conv_mfma_kernel<128, 1, true><<<dim3(T / 128, B), BDIM, 0, stream>>>(
        buf1, T, nullptr, nullptr, nullptr, wbs + (size_t)3 * WFRAGS * 8,
        P[20], P[21], P[22], P[23], P[24], energy);

    // pitch predictor on gather(x) + en_emb[eidx] -> pitch
    conv_mfma_kernel<128, 3, false><<<dim3(T / 128, B), BDIM, 0, stream>>>(
        x, T, gidx, eidx, en_emb, wbs + (size_t)4 * WFRAGS * 8,
        P[26], P[27], P[28], nullptr, nullptr, buf1);
    conv_mfma_kernel<128, 1, true><<<dim3(T / 128, B), BDIM, 0, stream>>>(
        buf1, T, nullptr, nullptr, nullptr, wbs + (size_t)5 * WFRAGS * 8,
        P[30], P[31], P[32], P[33], P[34], pitch);

    // final h = x[gidx] + en_emb + pi_emb (fp32)
    final_h_kernel<<<B * T / 4, BDIM, 0, stream>>>(
        x, gidx, eidx, pidx, en_emb, pi_emb, h);
}

// Round 5
// 222.035 us; speedup vs baseline: 7.1005x; 1.0230x over previous
//
#include <hip/hip_runtime.h>
#include <hip/hip_bf16.h>
#include <cstddef>

constexpr int B = 32, L = 512, D = 256, F = 256, T = 2048, NB = 256;
constexpr float LN_EPS = 1e-5f;
constexpr int BDIM = 256;
constexpr int WFRAGS = 24 * 16 * 64;     // MFMA B-fragments per conv layer
constexpr int STR = 264;                 // padded LDS row stride (shorts): 256+8

typedef __attribute__((ext_vector_type(8))) short short8;
typedef __attribute__((ext_vector_type(4))) float f32x4;

__device__ inline short f2bf(float x) {
    __hip_bfloat16 h = __float2bfloat16(x);
    return __builtin_bit_cast(short, h);
}

// ---------------- cumsum over durations (per batch row) ----------------
__global__ void cumsum_kernel(const int* __restrict__ dt, int* __restrict__ cum) {
    __shared__ int s[L];
    const int b = blockIdx.x, tid = threadIdx.x;
    s[tid] = dt[b * L + tid];
    __syncthreads();
    for (int off = 1; off < L; off <<= 1) {
        int v = (tid >= off) ? s[tid - off] : 0;
        __syncthreads();
        s[tid] += v;
        __syncthreads();
    }
    cum[b * L + tid] = s[tid];
}

// ------- all index precompute: gidx (LR gather), eidx, pidx (buckets) ----
__global__ void idx_kernel(const int* __restrict__ cum,
                           const float* __restrict__ et, const float* __restrict__ ebins,
                           const float* __restrict__ pt, const float* __restrict__ pbins,
                           int* __restrict__ gidx, int* __restrict__ eidx, int* __restrict__ pidx) {
    const int r = blockIdx.x * BDIM + threadIdx.x;       // r < B*T
    const int b = r >> 11, t = r & (T - 1);
    const int* c = cum + b * L;
    int lo = 0, hi = L;
    while (lo < hi) { const int mid = (lo + hi) >> 1; if (c[mid] <= t) lo = mid + 1; else hi = mid; }
    gidx[r] = (lo < L) ? lo : -1;
    const float e = et[r];
    int el = 0, eh = NB - 1;
    while (el < eh) { const int mid = (el + eh) >> 1; if (ebins[mid] < e) el = mid + 1; else eh = mid; }
    eidx[r] = el;
    const float p = pt[r];
    int pl = 0, ph = NB - 1;
    while (pl < ph) { const int mid = (pl + ph) >> 1; if (pbins[mid] < p) pl = mid + 1; else ph = mid; }
    pidx[r] = pl;
}

// -------- final h: x[gidx] + en_emb[eidx] + pi_emb[pidx], pure stream ----
__global__ void final_h_kernel(const float* __restrict__ x, const int* __restrict__ gidx,
                               const int* __restrict__ eidx, const int* __restrict__ pidx,
                               const float* __restrict__ eemb, const float* __restrict__ pemb,
                               float* __restrict__ h) {
    const int wave = threadIdx.x >> 6, lane = threadIdx.x & 63;
    const int row = blockIdx.x * 4 + wave;               // b*T + t
    const int b = row >> 11;
    const int g = gidx[row], ei = eidx[row], pi = pidx[row];
    float4 v = make_float4(0.f, 0.f, 0.f, 0.f);
    if (g >= 0) v = *(const float4*)(x + ((size_t)b * L + g) * D + lane * 4);
    const float4 ev = *(const float4*)(eemb + (size_t)ei * D + lane * 4);
    const float4 pv = *(const float4*)(pemb + (size_t)pi * D + lane * 4);
    v.x += ev.x + pv.x; v.y += ev.y + pv.y; v.z += ev.z + pv.z; v.w += ev.w + pv.w;
    *(float4*)(h + (size_t)row * D + lane * 4) = v;
}

// -------- weight repack (all 6 layers, one launch) -----------------------
__global__ void wprep_kernel(const float* __restrict__ w0, const float* __restrict__ w1,
                             const float* __restrict__ w2, const float* __restrict__ w3,
                             const float* __restrict__ w4, const float* __restrict__ w5,
                             short* __restrict__ wb) {
    const float* ws[6] = {w0, w1, w2, w3, w4, w5};
    const float* w = ws[blockIdx.y];
    short* dst = wb + (size_t)blockIdx.y * WFRAGS * 8;
    const int phi = blockIdx.x * BDIM + threadIdx.x;     // 0..24575
    const int kb = phi >> 10;
    const int n16 = (phi >> 6) & 15;
    const int lane = phi & 63;
    const int kconv = kb >> 3, dblk = kb & 7;
    const int kg = lane >> 4, fcol = n16 * 16 + (lane & 15);
    const float* src = w + (size_t)kconv * D * F + (dblk * 32 + kg * 8) * F + fcol;
    short8 o;
    #pragma unroll
    for (int j = 0; j < 8; j++) o[j] = f2bf(src[j * F]);
    *(short8*)(dst + (size_t)phi * 8) = o;
}

// ---- K=768 conv MFMA loop over a padded LDS tile (4 m-tiles x 4 n) ------
__device__ __forceinline__ void conv_kloop(const short* in_s, const short8* bw,
                                           short8 (&bnext)[4], f32x4 (&acc)[4][4],
                                           int w, int lane, int kg, int lr) {
    #pragma unroll 1
    for (int kb = 0; kb < 24; kb++) {
        const int kconv = kb >> 3, dblk = kb & 7;
        short8 bcur[4];
        #pragma unroll
        for (int n = 0; n < 4; n++) bcur[n] = bnext[n];
        if (kb < 23) {
            #pragma unroll
            for (int n = 0; n < 4; n++) bnext[n] = bw[((kb + 1) * 16 + w * 4 + n) * 64 + lane];
        }
        __builtin_amdgcn_s_setprio(1);
        #pragma unroll
        for (int m = 0; m < 4; m++) {
            const int row = m * 16 + lr + kconv;
            const short8 a = *(const short8*)(in_s + row * STR + dblk * 32 + kg * 8);
            #pragma unroll
            for (int n = 0; n < 4; n++)
                acc[m][n] = __builtin_amdgcn_mfma_f32_16x16x32_bf16(a, bcur[n], acc[m][n], 0, 0, 0);
        }
        __builtin_amdgcn_s_setprio(0);
    }
}

// ------- fully fused predictor: conv1+ReLU+LN1 -> conv2+ReLU+LN2+dot -----
// MODE 0: rows from fp32 [Tlen][256] directly (dur predictor on x)
// MODE 2: gather rows x[b, gidx[b*T+t], :] (energy predictor)
// MODE 3: gather + emb[eidx[b*T+t]] (pitch predictor)
// Block outputs 62 scalar rows [t0, t0+62); conv1 computes 64 halo rows.
template <int MODE>
__launch_bounds__(BDIM, 3)
__global__ void fused_pred_kernel(const float* __restrict__ xin, int Tlen,
                                  const int* __restrict__ gidx, const int* __restrict__ eidx,
                                  const float* __restrict__ emb,
                                  const short* __restrict__ wb1_, const short* __restrict__ wb2_,
                                  const float* __restrict__ cb1, const float* __restrict__ g1,
                                  const float* __restrict__ b1,
                                  const float* __restrict__ cb2, const float* __restrict__ g2,
                                  const float* __restrict__ b2,
                                  const float* __restrict__ lw, const float* __restrict__ lb,
                                  float* __restrict__ out) {
    __shared__ short in_s[66 * STR];            // 34.8 KB: x-tile, then conv1-LN tile
    __shared__ float red_s[4][64], red_q[4][64];
    __shared__ float row_m[64], row_rs[64];
    __shared__ float dot_p[4][64];

    const int b = blockIdx.y;
    const int t0 = blockIdx.x * 62;
    const int tid = threadIdx.x;
    const int w = tid >> 6, lane = tid & 63;
    const int kg = lane >> 4, lr = lane & 15;

    const short8* bw1 = (const short8*)wb1_;
    const short8* bw2 = (const short8*)wb2_;
    short8 bnext[4];
    #pragma unroll
    for (int n = 0; n < 4; n++) bnext[n] = bw1[(w * 4 + n) * 64 + lane];

    // ---- stage 66 input rows (t = t0-2 .. t0+63) as bf16, padded stride --
    constexpr int TASKS = 66 * 32;
    constexpr int BATCH = (MODE == 3) ? 2 : 4;
    for (int base = 0; base < TASKS; base += BATCH * BDIM) {
        float4 fa[BATCH], fb[BATCH], ea[BATCH], eb[BATCH];
        #pragma unroll
        for (int j = 0; j < BATCH; j++) {
            fa[j] = make_float4(0.f, 0.f, 0.f, 0.f); fb[j] = fa[j];
            ea[j] = fa[j]; eb[j] = fa[j];
            const int task = base + j * BDIM + tid;
            if (task < TASKS) {
                const int row = task >> 5, slot = task & 31;
                const int t = t0 - 2 + row;
                if (t >= 0 && t < Tlen) {
                    if constexpr (MODE == 0) {
                        const float* p = xin + ((size_t)b * Tlen + t) * D + slot * 8;
                        fa[j] = *(const float4*)p; fb[j] = *(const float4*)(p + 4);
                    } else {
                        const int g = gidx[b * T + t];
                        if (g >= 0) {
                            const float* p = xin + ((size_t)b * L + g) * D + slot * 8;
                            fa[j] = *(const float4*)p; fb[j] = *(const float4*)(p + 4);
                        }
                        if constexpr (MODE == 3) {
                            const float* er = emb + (size_t)eidx[b * T + t] * F + slot * 8;
                            ea[j] = *(const float4*)er; eb[j] = *(const float4*)(er + 4);
                        }
                    }
                }
            }
        }
        #pragma unroll
        for (int j = 0; j < BATCH; j++) {
            const int task = base + j * BDIM + tid;
            if (task < TASKS) {
                const int row = task >> 5, slot = task & 31;
                short8 frag;
                frag[0] = f2bf(fa[j].x + ea[j].x); frag[1] = f2bf(fa[j].y + ea[j].y);
                frag[2] = f2bf(fa[j].z + ea[j].z); frag[3] = f2bf(fa[j].w + ea[j].w);
                frag[4] = f2bf(fb[j].x + eb[j].x); frag[5] = f2bf(fb[j].y + eb[j].y);
                frag[6] = f2bf(fb[j].z + eb[j].z); frag[7] = f2bf(fb[j].w + eb[j].w);
                *(short8*)(in_s + row * STR + slot * 8) = frag;
            }
        }
    }
    __syncthreads();

    // ---- conv1 K-loop ----
    f32x4 acc[4][4];
    #pragma unroll
    for (int m = 0; m < 4; m++)
        #pragma unroll
        for (int n = 0; n < 4; n++)
            acc[m][n] = (f32x4){0.f, 0.f, 0.f, 0.f};
    conv_kloop(in_s, bw1, bnext, acc, w, lane, kg, lr);

    // prefetch conv2's first B-fragments (hides under epilogue1)
    #pragma unroll
    for (int n = 0; n < 4; n++) bnext[n] = bw2[(w * 4 + n) * 64 + lane];

    // ---- epilogue1: bias+ReLU, LN1 stats, write LN rows back to in_s ----
    float c1v[4], g1v[4], b1v[4];
    #pragma unroll
    for (int n = 0; n < 4; n++) {
        const int c = w * 64 + n * 16 + lr;
        c1v[n] = cb1[c]; g1v[n] = g1[c]; b1v[n] = b1[c];
    }
    #pragma unroll
    for (int m = 0; m < 4; m++) {
        #pragma unroll
        for (int reg = 0; reg < 4; reg++) {
            float s = 0.f, q = 0.f;
            #pragma unroll
            for (int n = 0; n < 4; n++) {
                const float v = fmaxf(acc[m][n][reg] + c1v[n], 0.f);
                acc[m][n][reg] = v;
                s += v; q += v * v;
            }
            #pragma unroll
            for (int msk = 1; msk < 16; msk <<= 1) { s += __shfl_xor(s, msk); q += __shfl_xor(q, msk); }
            if (lr == 0) {
                const int r = m * 16 + kg * 4 + reg;
                red_s[w][r] = s; red_q[w][r] = q;
            }
        }
    }
    __syncthreads();                                       // in_s (x-tile) now dead
    if (tid < 64) {
        const float s = red_s[0][tid] + red_s[1][tid] + red_s[2][tid] + red_s[3][tid];
        const float q = red_q[0][tid] + red_q[1][tid] + red_q[2][tid] + red_q[3][tid];
        const float mm = s * (1.f / 256.f);
        const float var = fmaxf(q * (1.f / 256.f) - mm * mm, 0.f);
        row_m[tid] = mm;
        row_rs[tid] = rsqrtf(var + LN_EPS);
    }
    if (tid >= 128 && tid < 194) {                         // zero c1 rows 64,65
        short8 z = {};
        *(short8*)(in_s + 64 * STR + (tid - 128) * 8) = z;
    }
    __syncthreads();

    // write LN1 rows (bf16) into in_s rows 0..63 (c1 row r1 <-> t0-1+r1)
    #pragma unroll
    for (int m = 0; m < 4; m++) {
        #pragma unroll
        for (int reg = 0; reg < 4; reg++) {
            const int r1 = m * 16 + kg * 4 + reg;
            const int tg = t0 - 1 + r1;
            const bool ok = (tg >= 0) && (tg < Tlen);
            const float mm = row_m[r1], rs = row_rs[r1];
            #pragma unroll
            for (int n = 0; n < 4; n++) {
                const int c = w * 64 + n * 16 + lr;
                const float v = ok ? (acc[m][n][reg] - mm) * rs * g1v[n] + b1v[n] : 0.f;
                in_s[r1 * STR + c] = f2bf(v);
            }
        }
    }
    __syncthreads();

    // ---- conv2 K-loop ----
    #pragma unroll
    for (int m = 0; m < 4; m++)
        #pragma unroll
        for (int n = 0; n < 4; n++)
            acc[m][n] = (f32x4){0.f, 0.f, 0.f, 0.f};
    conv_kloop(in_s, bw2, bnext, acc, w, lane, kg, lr);

    // ---- epilogue2: bias+ReLU, LN2 stats, dot(lw)+lb+ReLU -> scalar ----
    float c2v[4], g2v[4], b2v[4], lwv[4];
    #pragma unroll
    for (int n = 0; n < 4; n++) {
        const int c = w * 64 + n * 16 + lr;
        c2v[n] = cb2[c]; g2v[n] = g2[c]; b2v[n] = b2[c]; lwv[n] = lw[c];
    }
    #pragma unroll
    for (int m = 0; m < 4; m++) {
        #pragma unroll
        for (int reg = 0; reg < 4; reg++) {
            float s = 0.f, q = 0.f;
            #pragma unroll
            for (int n = 0; n < 4; n++) {
                const float v = fmaxf(acc[m][n][reg] + c2v[n], 0.f);
                acc[m][n][reg] = v;
                s += v; q += v * v;
            }
            #pragma unroll
            for (int msk = 1; msk < 16; msk <<= 1) { s += __shfl_xor(s, msk); q += __shfl_xor(q, msk); }
            if (lr == 0) {
                const int r = m * 16 + kg * 4 + reg;
                red_s[w][r] = s; red_q[w][r] = q;
            }
        }
    }
    __syncthreads();
    if (tid < 64) {
        const float s = red_s[0][tid] + red_s[1][tid] + red_s[2][tid] + red_s[3][tid];
        const float q = red_q[0][tid] + red_q[1][tid] + red_q[2][tid] + red_q[3][tid];
        const float mm = s * (1.f / 256.f);
        const float var = fmaxf(q * (1.f / 256.f) - mm * mm, 0.f);
        row_m[tid] = mm;
        row_rs[tid] = rsqrtf(var + LN_EPS);
    }
    __syncthreads();
    #pragma unroll
    for (int m = 0; m < 4; m++) {
        #pragma unroll
        for (int reg = 0; reg < 4; reg++) {
            const int r = m * 16 + kg * 4 + reg;
            const float mm = row_m[r], rs = row_rs[r];
            float p = 0.f;
            #pragma unroll
            for (int n = 0; n < 4; n++)
                p += ((acc[m][n][reg] - mm) * rs * g2v[n] + b2v[n]) * lwv[n];
            #pragma unroll
            for (int msk = 1; msk < 16; msk <<= 1) p += __shfl_xor(p, msk);
            if (lr == 0) dot_p[w][r] = p;
        }
    }
    __syncthreads();
    if (tid < 62) {
        const int t = t0 + tid;
        if (t < Tlen) {
            const float p = dot_p[0][tid] + dot_p[1][tid] + dot_p[2][tid] + dot_p[3][tid] + lb[0];
            out[(size_t)b * Tlen + t] = fmaxf(p, 0.f);
        }
    }
}

extern "C" void kernel_launch(void* const* d_in, const int* in_sizes, int n_in,
                              void* d_out, int out_size, void* d_ws, size_t ws_size,
                              hipStream_t stream) {
    const float* x        = (const float*)d_in[0];
    const int*   d_target = (const int*)d_in[1];
    const float* e_target = (const float*)d_in[2];
    const float* p_target = (const float*)d_in[3];

    const float* const* P = (const float* const*)d_in;
    const float* en_emb  = (const float*)d_in[35];
    const float* pi_emb  = (const float*)d_in[36];
    const float* en_bins = (const float*)d_in[37];
    const float* pi_bins = (const float*)d_in[38];

    float* out = (float*)d_out;
    float* h        = out;                                   // B*T*D fp32
    float* log_dur  = out + (size_t)B * T * D;               // B*L
    float* pitch    = log_dur + (size_t)B * L;               // B*T
    float* energy   = pitch + (size_t)B * T;                 // B*T

    // workspace layout (buf1 eliminated)
    short* wbs  = (short*)d_ws;                              // 6 * WFRAGS * 8 shorts
    int*   cum  = (int*)(wbs + (size_t)6 * WFRAGS * 8);      // B*L
    int*   gidx = cum + B * L;                               // B*T
    int*   eidx = gidx + B * T;                              // B*T
    int*   pidx = eidx + B * T;                              // B*T

    // weight repack (single launch, 6 layers)
    wprep_kernel<<<dim3(WFRAGS / BDIM, 6), BDIM, 0, stream>>>(
        P[5], P[9], P[15], P[19], P[25], P[29], wbs);

    cumsum_kernel<<<B, L, 0, stream>>>(d_target, cum);
    idx_kernel<<<B * T / BDIM, BDIM, 0, stream>>>(
        cum, e_target, en_bins, p_target, pi_bins, gidx, eidx, pidx);

    const short* wb_dur1 = wbs + (size_t)0 * WFRAGS * 8;
    const short* wb_dur2 = wbs + (size_t)1 * WFRAGS * 8;
    const short* wb_en1  = wbs + (size_t)2 * WFRAGS * 8;
    const short* wb_en2  = wbs + (size_t)3 * WFRAGS * 8;
    const short* wb_pi1  = wbs + (size_t)4 * WFRAGS * 8;
    const short* wb_pi2  = wbs + (size_t)5 * WFRAGS * 8;

    // duration predictor on x -> log_dur
    fused_pred_kernel<0><<<dim3((L + 61) / 62, B), BDIM, 0, stream>>>(
        x, L, nullptr, nullptr, nullptr, wb_dur1, wb_dur2,
        P[6], P[7], P[8], P[10], P[11], P[12], P[13], P[14], log_dur);

    // energy predictor on gather(x) -> energy
    fused_pred_kernel<2><<<dim3((T + 61) / 62, B), BDIM, 0, stream>>>(
        x, T, gidx, nullptr, nullptr, wb_en1, wb_en2,
        P[16], P[17], P[18], P[20], P[21], P[22], P[23], P[24], energy);

    // pitch predictor on gather(x) + en_emb[eidx] -> pitch
    fused_pred_kernel<3><<<dim3((T + 61) / 62, B), BDIM, 0, stream>>>(
        x, T, gidx, eidx, en_emb, wb_pi1, wb_pi2,
        P[26], P[27], P[28], P[30], P[31], P[32], P[33], P[34], pitch);

    // final h = x[gidx] + en_emb + pi_emb (fp32)
    final_h_kernel<<<B * T / 4, BDIM, 0, stream>>>(
        x, gidx, eidx, pidx, en_emb, pi_emb, h);
}

// Round 6
// 207.886 us; speedup vs baseline: 7.5837x; 1.0681x over previous
//
#include <hip/hip_runtime.h>
#include <hip/hip_bf16.h>
#include <cstddef>

constexpr int B = 32, L = 512, D = 256, F = 256, T = 2048, NB = 256;
constexpr float LN_EPS = 1e-5f;
constexpr int BDIM = 256;
constexpr int WFRAGS = 24 * 16 * 64;     // MFMA B-fragments per conv layer

typedef __attribute__((ext_vector_type(8))) short short8;
typedef __attribute__((ext_vector_type(4))) float f32x4;

__device__ inline short f2bf(float x) {
    __hip_bfloat16 h = __float2bfloat16(x);
    return __builtin_bit_cast(short, h);
}

// ---------------- cumsum over durations (per batch row) ----------------
__global__ void cumsum_kernel(const int* __restrict__ dt, int* __restrict__ cum) {
    __shared__ int s[L];
    const int b = blockIdx.x, tid = threadIdx.x;
    s[tid] = dt[b * L + tid];
    __syncthreads();
    for (int off = 1; off < L; off <<= 1) {
        int v = (tid >= off) ? s[tid - off] : 0;
        __syncthreads();
        s[tid] += v;
        __syncthreads();
    }
    cum[b * L + tid] = s[tid];
}

// ------- all index precompute: gidx (LR gather), eidx, pidx (buckets) ----
__global__ void idx_kernel(const int* __restrict__ cum,
                           const float* __restrict__ et, const float* __restrict__ ebins,
                           const float* __restrict__ pt, const float* __restrict__ pbins,
                           int* __restrict__ gidx, int* __restrict__ eidx, int* __restrict__ pidx) {
    const int r = blockIdx.x * BDIM + threadIdx.x;       // r < B*T
    const int b = r >> 11, t = r & (T - 1);
    const int* c = cum + b * L;
    int lo = 0, hi = L;
    while (lo < hi) { const int mid = (lo + hi) >> 1; if (c[mid] <= t) lo = mid + 1; else hi = mid; }
    gidx[r] = (lo < L) ? lo : -1;
    const float e = et[r];
    int el = 0, eh = NB - 1;
    while (el < eh) { const int mid = (el + eh) >> 1; if (ebins[mid] < e) el = mid + 1; else eh = mid; }
    eidx[r] = el;
    const float p = pt[r];
    int pl = 0, ph = NB - 1;
    while (pl < ph) { const int mid = (pl + ph) >> 1; if (pbins[mid] < p) pl = mid + 1; else ph = mid; }
    pidx[r] = pl;
}

// -------- final h: x[gidx] + en_emb[eidx] + pi_emb[pidx], pure stream ----
__global__ void final_h_kernel(const float* __restrict__ x, const int* __restrict__ gidx,
                               const int* __restrict__ eidx, const int* __restrict__ pidx,
                               const float* __restrict__ eemb, const float* __restrict__ pemb,
                               float* __restrict__ h) {
    const int wave = threadIdx.x >> 6, lane = threadIdx.x & 63;
    const int row = blockIdx.x * 4 + wave;               // b*T + t
    const int b = row >> 11;
    const int g = gidx[row], ei = eidx[row], pi = pidx[row];
    float4 v = make_float4(0.f, 0.f, 0.f, 0.f);
    if (g >= 0) v = *(const float4*)(x + ((size_t)b * L + g) * D + lane * 4);
    const float4 ev = *(const float4*)(eemb + (size_t)ei * D + lane * 4);
    const float4 pv = *(const float4*)(pemb + (size_t)pi * D + lane * 4);
    v.x += ev.x + pv.x; v.y += ev.y + pv.y; v.z += ev.z + pv.z; v.w += ev.w + pv.w;
    *(float4*)(h + (size_t)row * D + lane * 4) = v;
}

// -------- weight repack (all 6 layers, one launch) -----------------------
__global__ void wprep_kernel(const float* __restrict__ w0, const float* __restrict__ w1,
                             const float* __restrict__ w2, const float* __restrict__ w3,
                             const float* __restrict__ w4, const float* __restrict__ w5,
                             short* __restrict__ wb) {
    const float* ws[6] = {w0, w1, w2, w3, w4, w5};
    const float* w = ws[blockIdx.y];
    short* dst = wb + (size_t)blockIdx.y * WFRAGS * 8;
    const int phi = blockIdx.x * BDIM + threadIdx.x;     // 0..24575
    const int kb = phi >> 10;
    const int n16 = (phi >> 6) & 15;
    const int lane = phi & 63;
    const int kconv = kb >> 3, dblk = kb & 7;
    const int kg = lane >> 4, fcol = n16 * 16 + (lane & 15);
    const float* src = w + (size_t)kconv * D * F + (dblk * 32 + kg * 8) * F + fcol;
    short8 o;
    #pragma unroll
    for (int j = 0; j < 8; j++) o[j] = f2bf(src[j * F]);
    *(short8*)(dst + (size_t)phi * 8) = o;
}

// ---- K=768 conv MFMA loop; wave = 32 rows (wr) x 128 cols (wc) ----------
__device__ __forceinline__ void conv_kloop(const short* in_s, const short8* bw,
                                           f32x4 (&acc)[2][8], int wr, int wc,
                                           int lane, int kg, int lr) {
    short8 b0[4], b1[4];
    #pragma unroll
    for (int n = 0; n < 4; n++) b0[n] = bw[(wc * 8 + n) * 64 + lane];
    #pragma unroll
    for (int n = 0; n < 4; n++) b1[n] = bw[(wc * 8 + 4 + n) * 64 + lane];

    #pragma unroll 1
    for (int kb = 0; kb < 24; kb++) {
        const int kconv = kb >> 3, dblk = kb & 7;
        short8 a[2];
        #pragma unroll
        for (int m = 0; m < 2; m++) {
            const int row = wr * 32 + m * 16 + lr + kconv;
            a[m] = *(const short8*)(in_s + row * 256 + (((dblk * 4 + kg) ^ (row & 7)) << 3));
        }
        __builtin_amdgcn_s_setprio(1);
        #pragma unroll
        for (int m = 0; m < 2; m++)
            #pragma unroll
            for (int n = 0; n < 4; n++)
                acc[m][n] = __builtin_amdgcn_mfma_f32_16x16x32_bf16(a[m], b0[n], acc[m][n], 0, 0, 0);
        __builtin_amdgcn_s_setprio(0);
        if (kb < 23) {
            #pragma unroll
            for (int n = 0; n < 4; n++) b0[n] = bw[((kb + 1) * 16 + wc * 8 + n) * 64 + lane];
        }
        __builtin_amdgcn_s_setprio(1);
        #pragma unroll
        for (int m = 0; m < 2; m++)
            #pragma unroll
            for (int n = 0; n < 4; n++)
                acc[m][4 + n] = __builtin_amdgcn_mfma_f32_16x16x32_bf16(a[m], b1[n], acc[m][4 + n], 0, 0, 0);
        __builtin_amdgcn_s_setprio(0);
        if (kb < 23) {
            #pragma unroll
            for (int n = 0; n < 4; n++) b1[n] = bw[((kb + 1) * 16 + wc * 8 + 4 + n) * 64 + lane];
        }
    }
}

struct PredParams {
    const short* wb1; const short* wb2;
    const float *cb1, *g1, *b1, *cb2, *g2, *b2, *lw, *lb;
    const int* eidx; const float* emb;   // emb == nullptr -> no emb add
    float* out;
};

// ------- fully fused predictor: conv1+ReLU+LN1 -> conv2+ReLU+LN2+dot -----
// MODE 0: rows from fp32 [Tlen][256] directly (dur predictor on x)
// MODE 2: gather rows x[b, gidx[b*T+t], :] (+ optional emb[eidx])
// Block outputs 62 scalar rows [t0, t0+62); conv1 computes 64 halo rows.
template <int MODE>
__launch_bounds__(BDIM, 4)
__global__ void fused_pred_kernel(const float* __restrict__ xin, int Tlen,
                                  const int* __restrict__ gidx,
                                  PredParams p0, PredParams p1) {
    __shared__ short in_s[66 * 256];            // 33.8 KB: x-tile then conv1-LN tile
    __shared__ float red_s[4][64], red_q[4][64];
    __shared__ float row_m[64], row_rs[64];
    __shared__ float dot_p[4][64];

    const PredParams P = (blockIdx.z == 0) ? p0 : p1;
    const int b = blockIdx.y;
    const int t0 = blockIdx.x * 62;
    const int tid = threadIdx.x;
    const int w = tid >> 6, lane = tid & 63;
    const int wr = w >> 1, wc = w & 1;
    const int kg = lane >> 4, lr = lane & 15;

    const short8* bw1 = (const short8*)P.wb1;
    const short8* bw2 = (const short8*)P.wb2;

    // ---- stage 66 input rows (t = t0-2 .. t0+63) as bf16, XOR-swizzled ---
    constexpr int TASKS = 66 * 32;
    constexpr int BATCH = 4;
    const bool has_emb = (MODE != 0) && (P.emb != nullptr);
    for (int base = 0; base < TASKS; base += BATCH * BDIM) {
        float4 fa[BATCH], fb[BATCH], ea[BATCH], eb[BATCH];
        #pragma unroll
        for (int j = 0; j < BATCH; j++) {
            fa[j] = make_float4(0.f, 0.f, 0.f, 0.f); fb[j] = fa[j];
            ea[j] = fa[j]; eb[j] = fa[j];
            const int task = base + j * BDIM + tid;
            if (task < TASKS) {
                const int row = task >> 5, slot = task & 31;
                const int t = t0 - 2 + row;
                if (t >= 0 && t < Tlen) {
                    if constexpr (MODE == 0) {
                        const float* p = xin + ((size_t)b * Tlen + t) * D + slot * 8;
                        fa[j] = *(const float4*)p; fb[j] = *(const float4*)(p + 4);
                    } else {
                        const int g = gidx[b * T + t];
                        if (g >= 0) {
                            const float* p = xin + ((size_t)b * L + g) * D + slot * 8;
                            fa[j] = *(const float4*)p; fb[j] = *(const float4*)(p + 4);
                        }
                        if (has_emb) {
                            const float* er = P.emb + (size_t)P.eidx[b * T + t] * F + slot * 8;
                            ea[j] = *(const float4*)er; eb[j] = *(const float4*)(er + 4);
                        }
                    }
                }
            }
        }
        #pragma unroll
        for (int j = 0; j < BATCH; j++) {
            const int task = base + j * BDIM + tid;
            if (task < TASKS) {
                const int row = task >> 5, slot = task & 31;
                short8 frag;
                frag[0] = f2bf(fa[j].x + ea[j].x); frag[1] = f2bf(fa[j].y + ea[j].y);
                frag[2] = f2bf(fa[j].z + ea[j].z); frag[3] = f2bf(fa[j].w + ea[j].w);
                frag[4] = f2bf(fb[j].x + eb[j].x); frag[5] = f2bf(fb[j].y + eb[j].y);
                frag[6] = f2bf(fb[j].z + eb[j].z); frag[7] = f2bf(fb[j].w + eb[j].w);
                *(short8*)(in_s + row * 256 + ((slot ^ (row & 7)) << 3)) = frag;
            }
        }
    }
    __syncthreads();

    // ---- conv1 K-loop ----
    f32x4 acc[2][8];
    #pragma unroll
    for (int m = 0; m < 2; m++)
        #pragma unroll
        for (int n = 0; n < 8; n++)
            acc[m][n] = (f32x4){0.f, 0.f, 0.f, 0.f};
    conv_kloop(in_s, bw1, acc, wr, wc, lane, kg, lr);

    // ---- epilogue1: bias+ReLU, LN1 stats, write LN rows back to in_s ----
    float c1v[8], g1v[8], b1v[8];
    #pragma unroll
    for (int n = 0; n < 8; n++) {
        const int c = wc * 128 + n * 16 + lr;
        c1v[n] = P.cb1[c]; g1v[n] = P.g1[c]; b1v[n] = P.b1[c];
    }
    #pragma unroll
    for (int m = 0; m < 2; m++) {
        #pragma unroll
        for (int reg = 0; reg < 4; reg++) {
            float s = 0.f, q = 0.f;
            #pragma unroll
            for (int n = 0; n < 8; n++) {
                const float v = fmaxf(acc[m][n][reg] + c1v[n], 0.f);
                acc[m][n][reg] = v;
                s += v; q += v * v;
            }
            #pragma unroll
            for (int msk = 1; msk < 16; msk <<= 1) { s += __shfl_xor(s, msk); q += __shfl_xor(q, msk); }
            if (lr == 0) {
                const int r = wr * 32 + m * 16 + kg * 4 + reg;
                red_s[w][r] = s; red_q[w][r] = q;
            }
        }
    }
    __syncthreads();                                       // x-tile in in_s now dead
    if (tid < 64) {
        const int w0 = (tid >> 5) << 1;
        const float s = red_s[w0][tid] + red_s[w0 + 1][tid];
        const float q = red_q[w0][tid] + red_q[w0 + 1][tid];
        const float mm = s * (1.f / 256.f);
        const float var = fmaxf(q * (1.f / 256.f) - mm * mm, 0.f);
        row_m[tid] = mm;
        row_rs[tid] = rsqrtf(var + LN_EPS);
    }
    if (tid >= 128 && tid < 192) {                         // zero c1 rows 64,65
        short8 z = {};
        *(short8*)(in_s + 64 * 256 + (tid - 128) * 8) = z;
    }
    __syncthreads();

    // write LN1 rows (bf16) into in_s rows 0..63 (c1 row r1 <-> t0-1+r1)
    #pragma unroll
    for (int m = 0; m < 2; m++) {
        #pragma unroll
        for (int reg = 0; reg < 4; reg++) {
            const int r1 = wr * 32 + m * 16 + kg * 4 + reg;
            const int tg = t0 - 1 + r1;
            const bool ok = (tg >= 0) && (tg < Tlen);
            const float mm = row_m[r1], rs = row_rs[r1];
            #pragma unroll
            for (int n = 0; n < 8; n++) {
                const int c = wc * 128 + n * 16 + lr;
                const float v = ok ? (acc[m][n][reg] - mm) * rs * g1v[n] + b1v[n] : 0.f;
                in_s[r1 * 256 + (((c >> 3) ^ (r1 & 7)) << 3) + (c & 7)] = f2bf(v);
            }
        }
    }
    __syncthreads();

    // ---- conv2 K-loop ----
    #pragma unroll
    for (int m = 0; m < 2; m++)
        #pragma unroll
        for (int n = 0; n < 8; n++)
            acc[m][n] = (f32x4){0.f, 0.f, 0.f, 0.f};
    conv_kloop(in_s, bw2, acc, wr, wc, lane, kg, lr);

    // ---- epilogue2: bias+ReLU, LN2, dot(lw)+lb+ReLU -> scalar ----
    float c2v[8], g2v[8], b2v[8], lwv[8];
    #pragma unroll
    for (int n = 0; n < 8; n++) {
        const int c = wc * 128 + n * 16 + lr;
        c2v[n] = P.cb2[c]; g2v[n] = P.g2[c]; b2v[n] = P.b2[c]; lwv[n] = P.lw[c];
    }
    #pragma unroll
    for (int m = 0; m < 2; m++) {
        #pragma unroll
        for (int reg = 0; reg < 4; reg++) {
            float s = 0.f, q = 0.f;
            #pragma unroll
            for (int n = 0; n < 8; n++) {
                const float v = fmaxf(acc[m][n][reg] + c2v[n], 0.f);
                acc[m][n][reg] = v;
                s += v; q += v * v;
            }
            #pragma unroll
            for (int msk = 1; msk < 16; msk <<= 1) { s += __shfl_xor(s, msk); q += __shfl_xor(q, msk); }
            if (lr == 0) {
                const int r = wr * 32 + m * 16 + kg * 4 + reg;
                red_s[w][r] = s; red_q[w][r] = q;
            }
        }
    }
    __syncthreads();
    if (tid < 64) {
        const int w0 = (tid >> 5) << 1;
        const float s = red_s[w0][tid] + red_s[w0 + 1][tid];
        const float q = red_q[w0][tid] + red_q[w0 + 1][tid];
        const float mm = s * (1.f / 256.f);
        const float var = fmaxf(q * (1.f / 256.f) - mm * mm, 0.f);
        row_m[tid] = mm;
        row_rs[tid] = rsqrtf(var + LN_EPS);
    }
    __syncthreads();
    #pragma unroll
    for (int m = 0; m < 2; m++) {
        #pragma unroll
        for (int reg = 0; reg < 4; reg++) {
            const int r = wr * 32 + m * 16 + kg * 4 + reg;
            const float mm = row_m[r], rs = row_rs[r];
            float p = 0.f;
            #pragma unroll
            for (int n = 0; n < 8; n++)
                p += ((acc[m][n][reg] - mm) * rs * g2v[n] + b2v[n]) * lwv[n];
            #pragma unroll
            for (int msk = 1; msk < 16; msk <<= 1) p += __shfl_xor(p, msk);
            if (lr == 0) dot_p[w][r] = p;
        }
    }
    __syncthreads();
    if (tid < 62) {
        const int t = t0 + tid;
        if (t < Tlen) {
            const int w0 = (tid >> 5) << 1;
            const float p = dot_p[w0][tid] + dot_p[w0 + 1][tid] + P.lb[0];
            P.out[(size_t)b * Tlen + t] = fmaxf(p, 0.f);
        }
    }
}

extern "C" void kernel_launch(void* const* d_in, const int* in_sizes, int n_in,
                              void* d_out, int out_size, void* d_ws, size_t ws_size,
                              hipStream_t stream) {
    const float* x        = (const float*)d_in[0];
    const int*   d_target = (const int*)d_in[1];
    const float* e_target = (const float*)d_in[2];
    const float* p_target = (const float*)d_in[3];

    const float* const* P = (const float* const*)d_in;
    const float* en_emb  = (const float*)d_in[35];
    const float* pi_emb  = (const float*)d_in[36];
    const float* en_bins = (const float*)d_in[37];
    const float* pi_bins = (const float*)d_in[38];

    float* out = (float*)d_out;
    float* h        = out;                                   // B*T*D fp32
    float* log_dur  = out + (size_t)B * T * D;               // B*L
    float* pitch    = log_dur + (size_t)B * L;               // B*T
    float* energy   = pitch + (size_t)B * T;                 // B*T

    short* wbs  = (short*)d_ws;                              // 6 * WFRAGS * 8 shorts
    int*   cum  = (int*)(wbs + (size_t)6 * WFRAGS * 8);      // B*L
    int*   gidx = cum + B * L;                               // B*T
    int*   eidx = gidx + B * T;                              // B*T
    int*   pidx = eidx + B * T;                              // B*T

    wprep_kernel<<<dim3(WFRAGS / BDIM, 6), BDIM, 0, stream>>>(
        P[5], P[9], P[15], P[19], P[25], P[29], wbs);

    cumsum_kernel<<<B, L, 0, stream>>>(d_target, cum);
    idx_kernel<<<B * T / BDIM, BDIM, 0, stream>>>(
        cum, e_target, en_bins, p_target, pi_bins, gidx, eidx, pidx);

    PredParams dur_p = { wbs + (size_t)0 * WFRAGS * 8, wbs + (size_t)1 * WFRAGS * 8,
                         P[6], P[7], P[8], P[10], P[11], P[12], P[13], P[14],
                         nullptr, nullptr, log_dur };
    PredParams en_p  = { wbs + (size_t)2 * WFRAGS * 8, wbs + (size_t)3 * WFRAGS * 8,
                         P[16], P[17], P[18], P[20], P[21], P[22], P[23], P[24],
                         nullptr, nullptr, energy };
    PredParams pi_p  = { wbs + (size_t)4 * WFRAGS * 8, wbs + (size_t)5 * WFRAGS * 8,
                         P[26], P[27], P[28], P[30], P[31], P[32], P[33], P[34],
                         eidx, en_emb, pitch };

    // duration predictor on x -> log_dur
    fused_pred_kernel<0><<<dim3((L + 61) / 62, B, 1), BDIM, 0, stream>>>(
        x, L, nullptr, dur_p, dur_p);

    // energy (z=0) + pitch (z=1) predictors on gather(x) in ONE dispatch
    fused_pred_kernel<2><<<dim3((T + 61) / 62, B, 2), BDIM, 0, stream>>>(
        x, T, gidx, en_p, pi_p);

    // final h = x[gidx] + en_emb + pi_emb (fp32)
    final_h_kernel<<<B * T / 4, BDIM, 0, stream>>>(
        x, gidx, eidx, pidx, en_emb, pi_emb, h);
}